// Round 3
// baseline (3922.157 us; speedup 1.0000x reference)
//
#include <hip/hip_runtime.h>
#include <hip/hip_bf16.h>
#include <stdint.h>

#define NB 512
#define NW 40
#define NE 512
#define NH 512
#define NV 12000
#define G4 2048

typedef unsigned short u16;
typedef __attribute__((ext_vector_type(8))) short short8;
typedef __attribute__((ext_vector_type(4))) float f32x4;

__device__ __forceinline__ unsigned short f2bf(float f) {
  unsigned int u = __float_as_uint(f);
  u += 0x7FFF + ((u >> 16) & 1);
  return (unsigned short)(u >> 16);
}
__device__ __forceinline__ float bf2f(unsigned short b) {
  return __uint_as_float(((unsigned int)b) << 16);
}
__device__ __forceinline__ float loadIn(const void* p, long i, int bf) {
  return bf ? bf2f(((const u16*)p)[i]) : ((const float*)p)[i];
}

// ---------------- dtype detector ----------------
__global__ void detect_kernel(const u16* p, int* flag) {
  __shared__ int cnt;
  int i = threadIdx.x;
  if (i == 0) cnt = 0;
  __syncthreads();
  unsigned short u = p[2 * (i * 1001)];
  int e = (u >> 7) & 0xFF;
  if (e >= 100 && e <= 126) atomicAdd(&cnt, 1);
  __syncthreads();
  if (i == 0) *flag = (cnt >= 32) ? 1 : 0;
}

// ---------------- tableT = bf16(tanh(lookup_W^T)), (V, E) ----------------
__global__ void table_kernel(const void* lookup, const int* flag, u16* tableT) {
  __shared__ float tile[64][65];
  int bf = *flag;
  int v0 = blockIdx.x * 64, e0 = blockIdx.y * 64;
  int tx = threadIdx.x, ty = threadIdx.y;  // (64,4)
#pragma unroll
  for (int r = 0; r < 16; ++r) {
    int e = r * 4 + ty, v = tx;
    if (v0 + v < NV)
      tile[e][v] = tanhf(loadIn(lookup, (long)(e0 + e) * NV + v0 + v, bf));
  }
  __syncthreads();
#pragma unroll
  for (int r = 0; r < 16; ++r) {
    int v = r * 4 + ty, e = tx;
    if (v0 + v < NV)
      tableT[(long)(v0 + v) * NE + e0 + e] = f2bf(tile[e][v]);
  }
}

// ---------------- emb (W*B, E) bf16, rows tb = t*NB+b ----------------
__global__ void embed_kernel(const int* __restrict__ qv,
                             const u16* __restrict__ tableT,
                             u16* __restrict__ emb) {
  int tid = blockIdx.x * 256 + threadIdx.x;
  int token = tid >> 6;
  int chunk = tid & 63;
  int tt = token / NB, b = token % NB;
  int q = qv[b * NW + tt];
  uint4 val = make_uint4(0u, 0u, 0u, 0u);
  if (q > 0) val = *(const uint4*)(tableT + (long)(q - 1) * NE + chunk * 8);
  *(uint4*)(emb + (long)token * NE + chunk * 8) = val;
}

// ---------------- pack weights: Wc[d] rows = [wih | whh], bf16 ------------
__global__ void pack_kernel(const void* wih0, const void* whh0, const void* b0,
                            const void* wih1, const void* whh1, const void* b1,
                            const int* flag, u16* Wc0, u16* Wc1, float* bsum) {
  const long N0 = 2L * G4 * 1024, N1 = 2L * G4 * 1536;
  long idx = (long)blockIdx.x * 256 + threadIdx.x;
  int bf = *flag;
  if (idx < N0) {
    int d = (int)(idx / (G4 * 1024));
    int rem = (int)(idx % (long)(G4 * 1024));
    int g = rem / 1024, k = rem % 1024;
    float v = (k < 512) ? loadIn(wih0, ((long)d * G4 + g) * 512 + k, bf)
                        : loadIn(whh0, ((long)d * G4 + g) * 512 + (k - 512), bf);
    Wc0[idx] = f2bf(v);
  } else if (idx < N0 + N1) {
    long i2 = idx - N0;
    int d = (int)(i2 / (G4 * 1536));
    int rem = (int)(i2 % (long)(G4 * 1536));
    int g = rem / 1536, k = rem % 1536;
    float v = (k < 1024) ? loadIn(wih1, ((long)d * G4 + g) * 1024 + k, bf)
                         : loadIn(whh1, ((long)d * G4 + g) * 512 + (k - 1024), bf);
    Wc1[i2] = f2bf(v);
  } else if (idx < N0 + N1 + 2L * 2 * G4) {
    long i3 = idx - N0 - N1;  // [layer][d][g]
    int layer = (int)(i3 / (2 * G4));
    int d = (int)((i3 / G4) & 1);
    int g = (int)(i3 % G4);
    const void* bb = layer ? b1 : b0;
    float v = loadIn(bb, (long)d * 2 * G4 + g, bf) +
              loadIn(bb, (long)d * 2 * G4 + G4 + g, bf);
    bsum[i3] = v;
  }
}

// ---------------- zero the barrier (8 KB) ----------------
__global__ void zero_bar(unsigned int* bar) {
  bar[blockIdx.x * 256 + threadIdx.x] = 0u;
}

// ---------------- xg GEMM: xg[t][d][col][b][jn*4+g] = X@Wih^T + bias ------
// 128x128 tile, BK=64, m97-style single-buffer staging, 4 waves 2x2.
__global__ __launch_bounds__(256, 2) void xg_gemm(
    const u16* __restrict__ X, int Kx, int Kfull, const u16* __restrict__ Wc,
    const float* __restrict__ bsumL, u16* __restrict__ xg) {
  __shared__ __align__(16) char lds[32768];  // A 16K + B 16K
  const int tid = threadIdx.x;
  const int lane = tid & 63, wv = tid >> 6;
  const int wm = wv & 1, wn = wv >> 1;
  const int col = lane & 15, quad = lane >> 4;
  const int tb0 = blockIdx.x * 128;
  const int by = blockIdx.y;
  const int d = by >> 4, colb = by & 15, j0 = colb * 32;

  f32x4 zero = {0.f, 0.f, 0.f, 0.f};
  f32x4 acc[4][4];
#pragma unroll
  for (int i = 0; i < 4; ++i)
#pragma unroll
    for (int j = 0; j < 4; ++j) acc[i][j] = zero;

  const int iters = Kx >> 6;
  for (int it = 0; it < iters; ++it) {
    int k0 = it << 6;
#pragma unroll
    for (int p = 0; p < 8; ++p) {
      int c = p * 256 + tid;  // [0,2048)
      const u16* gsrc;
      if (c < 1024) {  // A rows 0..127
        int r = c >> 3, sl = c & 7;
        int kk = k0 + ((sl * 8) ^ ((r & 7) << 3));
        gsrc = X + (long)(tb0 + r) * Kx + kk;
      } else {
        int cb = c - 1024;
        int r = cb >> 3, sl = cb & 7;
        int kk = k0 + ((sl * 8) ^ ((r & 7) << 3));
        int grow = (r >> 5) * 512 + j0 + (r & 31);
        gsrc = Wc + ((long)d * G4 + grow) * Kfull + kk;
      }
      __builtin_amdgcn_global_load_lds(
          (const __attribute__((address_space(1))) void*)(const void*)gsrc,
          (__attribute__((address_space(3))) void*)(lds + p * 4096 + wv * 1024),
          16, 0, 0);
    }
    __syncthreads();
    const u16* As = (const u16*)lds;
    const u16* Bs = (const u16*)(lds + 16384);
#pragma unroll
    for (int ks = 0; ks < 2; ++ks) {
      short8 afr[4], bfr[4];
#pragma unroll
      for (int mf = 0; mf < 4; ++mf) {
        int rm = wm * 64 + mf * 16 + col;
        int sl = (ks * 32 + quad * 8) ^ ((rm & 7) << 3);
        afr[mf] = *(const short8*)(As + rm * 64 + sl);
      }
#pragma unroll
      for (int nf = 0; nf < 4; ++nf) {
        int br = wn * 64 + nf * 16 + col;
        int sl = (ks * 32 + quad * 8) ^ ((br & 7) << 3);
        bfr[nf] = *(const short8*)(Bs + br * 64 + sl);
      }
#pragma unroll
      for (int mf = 0; mf < 4; ++mf)
#pragma unroll
        for (int nf = 0; nf < 4; ++nf)
          acc[mf][nf] = __builtin_amdgcn_mfma_f32_16x16x32_bf16(
              afr[mf], bfr[nf], acc[mf][nf], 0, 0, 0);
    }
    __syncthreads();
  }

  float bias[4];
#pragma unroll
  for (int nf = 0; nf < 4; ++nf) {
    int n = wn * 64 + nf * 16 + col;
    bias[nf] = bsumL[d * G4 + (n >> 5) * 512 + j0 + (n & 31)];
  }
#pragma unroll
  for (int mf = 0; mf < 4; ++mf)
#pragma unroll
    for (int nf = 0; nf < 4; ++nf) {
      int n = wn * 64 + nf * 16 + col;
      int g = n >> 5, jn = n & 31;
#pragma unroll
      for (int r = 0; r < 4; ++r) {
        int m = wm * 64 + mf * 16 + quad * 4 + r;
        int tb = tb0 + m, t = tb >> 9, b = tb & 511;
        long oi = ((((long)t * 2 + d) * 16 + colb) * 512 + b) * 128 + jn * 4 + g;
        xg[oi] = f2bf(acc[mf][nf][r] + bias[nf]);
      }
    }
}

// ---------------- persistent bidirectional LSTM recurrence ----------------
// 256 blocks (1/CU: 144 KB LDS). Block = (mi [0,8) x colid [0,32)):
// 64 batch x (4 gates x 32 j) for dir d = colid>>4. Whh slice (128x512 bf16,
// 128 KB) resident in LDS for all 40 steps. h fragments loaded direct to
// registers (no K-loop barriers). c in registers. Tree barrier between steps.
__global__ __launch_bounds__(256, 1) void lstm_recur(
    const u16* __restrict__ xg, const u16* __restrict__ Wc, int Kfull, int Kx,
    u16* __restrict__ hbuf, u16* __restrict__ h0cat, void* __restrict__ outp,
    const int* __restrict__ qlen, const int* __restrict__ flag,
    unsigned int* bar, int layer) {
  __shared__ __align__(16) char lds[147456];  // [Whh 128K][gates 16K]
  const int tid = threadIdx.x;
  const int lane = tid & 63, wv = tid >> 6;
  const int wm = wv & 1, wn = wv >> 1;
  const int col = lane & 15, quad = lane >> 4;
  const int l = blockIdx.x;
  const int colid = l & 31, mi = l >> 5;
  const int j0 = (colid & 15) * 32, d = colid >> 4;
  const int m0 = mi * 64;

  // ---- preload Whh slice into LDS: rows r=g*32+jn, [128][512] swizzled ----
#pragma unroll
  for (int p = 0; p < 32; ++p) {
    int c = p * 256 + tid;
    int row = c >> 6, rem = c & 63;
    int kc = rem >> 3, sl = rem & 7;
    int grow = (row >> 5) * 512 + j0 + (row & 31);
    int gk = Kx + kc * 64 + ((sl * 8) ^ ((row & 7) << 3));
    const u16* gsrc = Wc + ((long)d * G4 + grow) * Kfull + gk;
    __builtin_amdgcn_global_load_lds(
        (const __attribute__((address_space(1))) void*)(const void*)gsrc,
        (__attribute__((address_space(3))) void*)(lds + p * 4096 + wv * 1024),
        16, 0, 0);
  }
  __syncthreads();
  const u16* Bs = (const u16*)lds;
  float* GL = (float*)(lds + 131072);  // [2][64][32] fp32

  float creg[8];
#pragma unroll
  for (int i = 0; i < 8; ++i) creg[i] = 0.f;
  const int isbf = *flag;
  f32x4 zero = {0.f, 0.f, 0.f, 0.f};

#pragma unroll 1
  for (int t = 0; t < NW; ++t) {
    const int tq = d ? (NW - 1 - t) : t;  // original timestep for this dir
    // prefetch xg tile (includes bias): thread -> (m = p*8 + tid>>5, n=tid&31)
    ushort4 xgv[8];
    const u16* xgt =
        xg + ((((long)tq * 2 + d) * 16 + (colid & 15)) * 512 + m0) * 128;
#pragma unroll
    for (int p = 0; p < 8; ++p) {
      int m = p * 8 + (tid >> 5), n = tid & 31;
      xgv[p] = *(const ushort4*)(xgt + m * 128 + n * 4);
    }

    f32x4 acc[2][4];
#pragma unroll
    for (int i = 0; i < 2; ++i)
#pragma unroll
      for (int j = 0; j < 4; ++j) acc[i][j] = zero;

    if (t > 0) {
      const u16* hp = hbuf + ((t - 1) & 1) * (2 * NB * NH) + (long)d * NB * NH;
#pragma unroll
      for (int it = 0; it < 8; ++it) {
#pragma unroll
        for (int ks = 0; ks < 2; ++ks) {
          short8 afr[2], bfr[4];
#pragma unroll
          for (int mf = 0; mf < 2; ++mf) {
            int rm = m0 + wm * 32 + mf * 16 + col;
            afr[mf] =
                *(const short8*)(hp + (long)rm * NH + it * 64 + ks * 32 + quad * 8);
          }
#pragma unroll
          for (int nf = 0; nf < 4; ++nf) {
            int br = wn * 64 + nf * 16 + col;
            int sl = (ks * 32 + quad * 8) ^ ((br & 7) << 3);
            bfr[nf] = *(const short8*)(Bs + br * 512 + it * 64 + sl);
          }
#pragma unroll
          for (int mf = 0; mf < 2; ++mf)
#pragma unroll
            for (int nf = 0; nf < 4; ++nf)
              acc[mf][nf] = __builtin_amdgcn_mfma_f32_16x16x32_bf16(
                  afr[mf], bfr[nf], acc[mf][nf], 0, 0, 0);
        }
      }
    }

    // ---- two-phase gate exchange through 16 KB LDS ----
    // phase 1: wn==0 waves hold gates 0(i),1(f)
    if (wn == 0) {
#pragma unroll
      for (int mf = 0; mf < 2; ++mf)
#pragma unroll
        for (int nf = 0; nf < 4; ++nf) {
          int n = nf * 16 + col;  // 0..63: g=n>>5, jn=n&31
#pragma unroll
          for (int r = 0; r < 4; ++r) {
            int m = wm * 32 + mf * 16 + quad * 4 + r;
            GL[((n >> 5) * 64 + m) * 32 + (n & 31)] = acc[mf][nf][r];
          }
        }
    }
    __syncthreads();
    float si[8], sf[8];
#pragma unroll
    for (int p = 0; p < 8; ++p) {
      int m = p * 8 + (tid >> 5), n = tid & 31;
      float gi = GL[(0 * 64 + m) * 32 + n] + bf2f(xgv[p].x);
      float gf = GL[(1 * 64 + m) * 32 + n] + bf2f(xgv[p].y);
      si[p] = 1.f / (1.f + __expf(-gi));
      sf[p] = 1.f / (1.f + __expf(-gf));
    }
    __syncthreads();
    if (wn == 1) {  // gates 2(g),3(o)
#pragma unroll
      for (int mf = 0; mf < 2; ++mf)
#pragma unroll
        for (int nf = 0; nf < 4; ++nf) {
          int n = 64 + nf * 16 + col;  // 64..127: g=n>>5 (2,3)
#pragma unroll
          for (int r = 0; r < 4; ++r) {
            int m = wm * 32 + mf * 16 + quad * 4 + r;
            GL[(((n >> 5) - 2) * 64 + m) * 32 + (n & 31)] = acc[mf][nf][r];
          }
        }
    }
    __syncthreads();
#pragma unroll
    for (int p = 0; p < 8; ++p) {
      int m = p * 8 + (tid >> 5), n = tid & 31;
      float gg = GL[(0 * 64 + m) * 32 + n] + bf2f(xgv[p].z);
      float go = GL[(1 * 64 + m) * 32 + n] + bf2f(xgv[p].w);
      float cn = sf[p] * creg[p] + si[p] * tanhf(gg);
      float so = 1.f / (1.f + __expf(-go));
      float h = so * tanhf(cn);
      creg[p] = cn;
      int bg = m0 + m, jg = j0 + n;
      hbuf[(t & 1) * (2 * NB * NH) + ((long)d * NB + bg) * NH + jg] = f2bf(h);
      if (layer == 0) {
        h0cat[((long)tq * NB + bg) * (2 * NH) + d * NH + jg] = f2bf(h);
      } else if (qlen[bg] - 1 == tq) {
        long oi = (long)bg * (2 * NH) + d * NH + jg;
        if (isbf)
          ((u16*)outp)[oi] = f2bf(h);
        else
          ((float*)outp)[oi] = h;
      }
    }

    // ---- grid barrier (2-level tree, device scope) ----
    if (t < NW - 1) {
      __threadfence();
      __syncthreads();
      if (tid == 0) {
        unsigned lo = atomicAdd(&bar[(l & 31) * 16], 1u);
        if (lo == 8u * (t + 1) - 1) {
          unsigned ro = atomicAdd(&bar[1024], 1u);
          if (ro == 32u * (t + 1) - 1)
            __hip_atomic_store(&bar[1040], (unsigned)(t + 1), __ATOMIC_RELEASE,
                               __HIP_MEMORY_SCOPE_AGENT);
        }
        while (__hip_atomic_load(&bar[1040], __ATOMIC_RELAXED,
                                 __HIP_MEMORY_SCOPE_AGENT) < (unsigned)(t + 1))
          __builtin_amdgcn_s_sleep(2);
      }
      __syncthreads();
      __threadfence();
    }
  }
}

extern "C" void kernel_launch(void* const* d_in, const int* in_sizes, int n_in,
                              void* d_out, int out_size, void* d_ws,
                              size_t ws_size, hipStream_t stream) {
  const int* qv = (const int*)d_in[0];
  const int* ql = (const int*)d_in[1];
  const void* lookup = d_in[2];
  const void* wih0 = d_in[3];
  const void* whh0 = d_in[4];
  const void* b0 = d_in[5];
  const void* wih1 = d_in[6];
  const void* whh1 = d_in[7];
  const void* b1 = d_in[8];

  char* ws = (char*)d_ws;
  size_t off = 0;
  int* flag = (int*)ws;                 off += 256;
  unsigned int* bar = (unsigned int*)(ws + off); off += 8192;
  float* bsum = (float*)(ws + off);     off += 2L * 2 * G4 * 4;        // 32 KB
  u16* Wc0 = (u16*)(ws + off);          off += 2L * G4 * 1024 * 2;     // 8 MB
  u16* Wc1 = (u16*)(ws + off);          off += 2L * G4 * 1536 * 2;     // 12 MB
  u16* hbuf = (u16*)(ws + off);         off += 2L * 2 * NB * NH * 2;   // 2 MB
  u16* h0cat = (u16*)(ws + off);        off += (size_t)NW * NB * 2 * NH * 2; // 40 MB
  u16* emb = (u16*)(ws + off);          off += (size_t)NW * NB * NE * 2;     // 20 MB
  u16* xg = (u16*)(ws + off);           off += (size_t)NW * 2 * 16 * 512 * 128 * 2; // 160 MB
  u16* tableT = h0cat;  // tableT (12.3 MB) aliases h0cat: dead before recur0

  detect_kernel<<<1, 64, 0, stream>>>((const u16*)lookup, flag);
  table_kernel<<<dim3(188, 8), dim3(64, 4), 0, stream>>>(lookup, flag, tableT);
  {
    long total = 2L * G4 * 1024 + 2L * G4 * 1536 + 2L * 2 * G4;
    int blocks = (int)((total + 255) / 256);
    pack_kernel<<<blocks, 256, 0, stream>>>(wih0, whh0, b0, wih1, whh1, b1,
                                            flag, Wc0, Wc1, bsum);
  }
  embed_kernel<<<NW * NB / 4, 256, 0, stream>>>(qv, tableT, emb);

  // layer 0: input projection GEMM, then persistent recurrence
  xg_gemm<<<dim3(160, 32), 256, 0, stream>>>(emb, 512, 1024, Wc0, bsum, xg);
  zero_bar<<<8, 256, 0, stream>>>(bar);
  lstm_recur<<<256, 256, 0, stream>>>(xg, Wc0, 1024, 512, hbuf, h0cat, d_out,
                                      ql, flag, bar, 0);
  // layer 1
  xg_gemm<<<dim3(160, 32), 256, 0, stream>>>(h0cat, 1024, 1536, Wc1,
                                             bsum + 2 * G4, xg);
  zero_bar<<<8, 256, 0, stream>>>(bar);
  lstm_recur<<<256, 256, 0, stream>>>(xg, Wc1, 1536, 1024, hbuf, h0cat, d_out,
                                      ql, flag, bar, 1);
}

// Round 4
// 1448.620 us; speedup vs baseline: 2.7075x; 2.7075x over previous
//
#include <hip/hip_runtime.h>
#include <hip/hip_bf16.h>
#include <stdint.h>

#define NB 512
#define NW 40
#define NE 512
#define NH 512
#define NV 12000
#define G4 2048

typedef unsigned short u16;
typedef __attribute__((ext_vector_type(8))) short short8;
typedef __attribute__((ext_vector_type(4))) float f32x4;

__device__ __forceinline__ unsigned short f2bf(float f) {
  unsigned int u = __float_as_uint(f);
  u += 0x7FFF + ((u >> 16) & 1);
  return (unsigned short)(u >> 16);
}
__device__ __forceinline__ float bf2f(unsigned short b) {
  return __uint_as_float(((unsigned int)b) << 16);
}
__device__ __forceinline__ float loadIn(const void* p, long i, int bf) {
  return bf ? bf2f(((const u16*)p)[i]) : ((const float*)p)[i];
}

// ---------------- dtype detector ----------------
__global__ void detect_kernel(const u16* p, int* flag) {
  __shared__ int cnt;
  int i = threadIdx.x;
  if (i == 0) cnt = 0;
  __syncthreads();
  unsigned short u = p[2 * (i * 1001)];
  int e = (u >> 7) & 0xFF;
  if (e >= 100 && e <= 126) atomicAdd(&cnt, 1);
  __syncthreads();
  if (i == 0) *flag = (cnt >= 32) ? 1 : 0;
}

// ---------------- tableT = bf16(tanh(lookup_W^T)), (V, E) ----------------
__global__ void table_kernel(const void* lookup, const int* flag, u16* tableT) {
  __shared__ float tile[64][65];
  int bf = *flag;
  int v0 = blockIdx.x * 64, e0 = blockIdx.y * 64;
  int tx = threadIdx.x, ty = threadIdx.y;  // (64,4)
#pragma unroll
  for (int r = 0; r < 16; ++r) {
    int e = r * 4 + ty, v = tx;
    if (v0 + v < NV)
      tile[e][v] = tanhf(loadIn(lookup, (long)(e0 + e) * NV + v0 + v, bf));
  }
  __syncthreads();
#pragma unroll
  for (int r = 0; r < 16; ++r) {
    int v = r * 4 + ty, e = tx;
    if (v0 + v < NV)
      tableT[(long)(v0 + v) * NE + e0 + e] = f2bf(tile[e][v]);
  }
}

// ---------------- emb (W*B, E) bf16, rows tb = t*NB+b ----------------
__global__ void embed_kernel(const int* __restrict__ qv,
                             const u16* __restrict__ tableT,
                             u16* __restrict__ emb) {
  int tid = blockIdx.x * 256 + threadIdx.x;
  int token = tid >> 6;
  int chunk = tid & 63;
  int tt = token / NB, b = token % NB;
  int q = qv[b * NW + tt];
  uint4 val = make_uint4(0u, 0u, 0u, 0u);
  if (q > 0) val = *(const uint4*)(tableT + (long)(q - 1) * NE + chunk * 8);
  *(uint4*)(emb + (long)token * NE + chunk * 8) = val;
}

// ---------------- pack weights: Wc[d] rows = [wih | whh], bf16 ------------
__global__ void pack_kernel(const void* wih0, const void* whh0, const void* b0,
                            const void* wih1, const void* whh1, const void* b1,
                            const int* flag, u16* Wc0, u16* Wc1, float* bsum) {
  const long N0 = 2L * G4 * 1024, N1 = 2L * G4 * 1536;
  long idx = (long)blockIdx.x * 256 + threadIdx.x;
  int bf = *flag;
  if (idx < N0) {
    int d = (int)(idx / (G4 * 1024));
    int rem = (int)(idx % (long)(G4 * 1024));
    int g = rem / 1024, k = rem % 1024;
    float v = (k < 512) ? loadIn(wih0, ((long)d * G4 + g) * 512 + k, bf)
                        : loadIn(whh0, ((long)d * G4 + g) * 512 + (k - 512), bf);
    Wc0[idx] = f2bf(v);
  } else if (idx < N0 + N1) {
    long i2 = idx - N0;
    int d = (int)(i2 / (G4 * 1536));
    int rem = (int)(i2 % (long)(G4 * 1536));
    int g = rem / 1536, k = rem % 1536;
    float v = (k < 1024) ? loadIn(wih1, ((long)d * G4 + g) * 1024 + k, bf)
                         : loadIn(whh1, ((long)d * G4 + g) * 512 + (k - 1024), bf);
    Wc1[i2] = f2bf(v);
  } else if (idx < N0 + N1 + 2L * 2 * G4) {
    long i3 = idx - N0 - N1;  // [layer][d][g]
    int layer = (int)(i3 / (2 * G4));
    int d = (int)((i3 / G4) & 1);
    int g = (int)(i3 % G4);
    const void* bb = layer ? b1 : b0;
    float v = loadIn(bb, (long)d * 2 * G4 + g, bf) +
              loadIn(bb, (long)d * 2 * G4 + G4 + g, bf);
    bsum[i3] = v;
  }
}

// ---------------- xg GEMM: xg[t][d][col][b][jn*4+g] = X@Wih^T + bias ------
// 128x128 tile, BK=64, m97-style staging, 4 waves 2x2. (R3-validated.)
__global__ __launch_bounds__(256, 2) void xg_gemm(
    const u16* __restrict__ X, int Kx, int Kfull, const u16* __restrict__ Wc,
    const float* __restrict__ bsumL, u16* __restrict__ xg) {
  __shared__ __align__(16) char lds[32768];  // A 16K + B 16K
  const int tid = threadIdx.x;
  const int lane = tid & 63, wv = tid >> 6;
  const int wm = wv & 1, wn = wv >> 1;
  const int col = lane & 15, quad = lane >> 4;
  const int tb0 = blockIdx.x * 128;
  const int by = blockIdx.y;
  const int d = by >> 4, colb = by & 15, j0 = colb * 32;

  f32x4 zero = {0.f, 0.f, 0.f, 0.f};
  f32x4 acc[4][4];
#pragma unroll
  for (int i = 0; i < 4; ++i)
#pragma unroll
    for (int j = 0; j < 4; ++j) acc[i][j] = zero;

  const int iters = Kx >> 6;
  for (int it = 0; it < iters; ++it) {
    int k0 = it << 6;
#pragma unroll
    for (int p = 0; p < 8; ++p) {
      int c = p * 256 + tid;  // [0,2048)
      const u16* gsrc;
      if (c < 1024) {  // A rows 0..127
        int r = c >> 3, sl = c & 7;
        int kk = k0 + ((sl * 8) ^ ((r & 7) << 3));
        gsrc = X + (long)(tb0 + r) * Kx + kk;
      } else {
        int cb = c - 1024;
        int r = cb >> 3, sl = cb & 7;
        int kk = k0 + ((sl * 8) ^ ((r & 7) << 3));
        int grow = (r >> 5) * 512 + j0 + (r & 31);
        gsrc = Wc + ((long)d * G4 + grow) * Kfull + kk;
      }
      __builtin_amdgcn_global_load_lds(
          (const __attribute__((address_space(1))) void*)(const void*)gsrc,
          (__attribute__((address_space(3))) void*)(lds + p * 4096 + wv * 1024),
          16, 0, 0);
    }
    __syncthreads();
    const u16* As = (const u16*)lds;
    const u16* Bs = (const u16*)(lds + 16384);
#pragma unroll
    for (int ks = 0; ks < 2; ++ks) {
      short8 afr[4], bfr[4];
#pragma unroll
      for (int mf = 0; mf < 4; ++mf) {
        int rm = wm * 64 + mf * 16 + col;
        int sl = (ks * 32 + quad * 8) ^ ((rm & 7) << 3);
        afr[mf] = *(const short8*)(As + rm * 64 + sl);
      }
#pragma unroll
      for (int nf = 0; nf < 4; ++nf) {
        int br = wn * 64 + nf * 16 + col;
        int sl = (ks * 32 + quad * 8) ^ ((br & 7) << 3);
        bfr[nf] = *(const short8*)(Bs + br * 64 + sl);
      }
#pragma unroll
      for (int mf = 0; mf < 4; ++mf)
#pragma unroll
        for (int nf = 0; nf < 4; ++nf)
          acc[mf][nf] = __builtin_amdgcn_mfma_f32_16x16x32_bf16(
              afr[mf], bfr[nf], acc[mf][nf], 0, 0, 0);
    }
    __syncthreads();
  }

  float bias[4];
#pragma unroll
  for (int nf = 0; nf < 4; ++nf) {
    int n = wn * 64 + nf * 16 + col;
    bias[nf] = bsumL[d * G4 + (n >> 5) * 512 + j0 + (n & 31)];
  }
#pragma unroll
  for (int mf = 0; mf < 4; ++mf)
#pragma unroll
    for (int nf = 0; nf < 4; ++nf) {
      int n = wn * 64 + nf * 16 + col;
      int g = n >> 5, jn = n & 31;
#pragma unroll
      for (int r = 0; r < 4; ++r) {
        int m = wm * 64 + mf * 16 + quad * 4 + r;
        int tb = tb0 + m, t = tb >> 9, b = tb & 511;
        long oi = ((((long)t * 2 + d) * 16 + colb) * 512 + b) * 128 + jn * 4 + g;
        xg[oi] = f2bf(acc[mf][nf][r] + bias[nf]);
      }
    }
}

// ---------------- per-step recurrent GEMM + cell update ----------------
// 256 blocks: l -> colid (16 j-cols x 2 dirs) x mi (8 m-blocks of 64 batch).
// B = Whh slice (128 gate-rows x 64 k) dbuf-staged via global_load_lds;
// A = h_{t-1} fragments loaded direct to registers (R3-validated math).
// Epilogue: gate exchange via LDS, fused LSTM cell, h/out writes.
__global__ __launch_bounds__(256, 2) void hstep(
    const u16* __restrict__ xg, const u16* __restrict__ Wc, int Kfull, int Kx,
    u16* __restrict__ hbuf, u16* __restrict__ h0cat, void* __restrict__ outp,
    const int* __restrict__ qlen, const int* __restrict__ flag,
    float* __restrict__ cst, int t, int layer) {
  __shared__ __align__(16) char lds[32768];  // dbuf 2x16K; epilogue 32K
  const int tid = threadIdx.x;
  const int lane = tid & 63, wv = tid >> 6;
  const int wm = wv & 1, wn = wv >> 1;
  const int col = lane & 15, quad = lane >> 4;
  const int l = blockIdx.x;
  const int colid = l & 31, mi = l >> 5;
  const int colb = colid & 15, j0 = colb * 32, d = colid >> 4;
  const int m0 = mi * 64;
  const int tq = d ? (NW - 1 - t) : t;

  // prefetch xg tile (includes bias) + c state, hidden under the K-loop
  ushort4 xgv[8];
  const u16* xgt = xg + ((((long)tq * 2 + d) * 16 + colb) * 512 + m0) * 128;
#pragma unroll
  for (int p = 0; p < 8; ++p) {
    int m = p * 8 + (tid >> 5), n = tid & 31;
    xgv[p] = *(const ushort4*)(xgt + m * 128 + n * 4);
  }
  float cold[8];
  if (t > 0) {
#pragma unroll
    for (int p = 0; p < 8; ++p) {
      int m = p * 8 + (tid >> 5), n = tid & 31;
      cold[p] = cst[((long)d * NB + m0 + m) * NH + j0 + n];
    }
  } else {
#pragma unroll
    for (int p = 0; p < 8; ++p) cold[p] = 0.f;
  }

  f32x4 zero = {0.f, 0.f, 0.f, 0.f};
  f32x4 acc[2][4];
#pragma unroll
  for (int i = 0; i < 2; ++i)
#pragma unroll
    for (int j = 0; j < 4; ++j) acc[i][j] = zero;

  if (t > 0) {
    const u16* hp;
    long hstr;
    if (layer == 0) {  // h lives interleaved in h0cat
      int tp = d ? (NW - t) : (t - 1);
      hp = h0cat + (long)tp * NB * (2 * NH) + d * NH;
      hstr = 2 * NH;
    } else {
      hp = hbuf + ((t - 1) & 1) * (2L * NB * NH) + (long)d * NB * NH;
      hstr = NH;
    }
    // stage B tile (128 rows x 64 k = 16KB) for k-iter `it` into buf pb
    auto stage = [&](int it, int pb) {
      char* dst = lds + pb * 16384;
#pragma unroll
      for (int p = 0; p < 4; ++p) {
        int c = p * 256 + tid;  // [0,1024)
        int br = c >> 3, sl = c & 7;
        int kk = Kx + it * 64 + ((sl * 8) ^ ((br & 7) << 3));
        const u16* gsrc =
            Wc + ((long)d * G4 + (br >> 5) * 512 + j0 + (br & 31)) * Kfull + kk;
        __builtin_amdgcn_global_load_lds(
            (const __attribute__((address_space(1))) void*)(const void*)gsrc,
            (__attribute__((address_space(3))) void*)(dst + p * 4096 +
                                                      wv * 1024),
            16, 0, 0);
      }
    };
    int pb = 0;
    stage(0, 0);
    __syncthreads();
#pragma unroll 1
    for (int it = 0; it < 8; ++it) {
      if (it + 1 < 8) stage(it + 1, pb ^ 1);
      const u16* Bs = (const u16*)(lds + pb * 16384);
#pragma unroll
      for (int ks = 0; ks < 2; ++ks) {
        short8 afr[2], bfr[4];
#pragma unroll
        for (int mf = 0; mf < 2; ++mf) {
          int rm = m0 + wm * 32 + mf * 16 + col;
          afr[mf] =
              *(const short8*)(hp + (long)rm * hstr + it * 64 + ks * 32 +
                               quad * 8);
        }
#pragma unroll
        for (int nf = 0; nf < 4; ++nf) {
          int br = wn * 64 + nf * 16 + col;
          int sl = (ks * 32 + quad * 8) ^ ((br & 7) << 3);
          bfr[nf] = *(const short8*)(Bs + br * 64 + sl);
        }
#pragma unroll
        for (int mf = 0; mf < 2; ++mf)
#pragma unroll
          for (int nf = 0; nf < 4; ++nf)
            acc[mf][nf] = __builtin_amdgcn_mfma_f32_16x16x32_bf16(
                afr[mf], bfr[nf], acc[mf][nf], 0, 0, 0);
      }
      __syncthreads();
      pb ^= 1;
    }
  }

  // ---- gates -> LDS fp32 [gate][64 m][32 n] = 32 KB ----
  float* L = (float*)lds;
#pragma unroll
  for (int mf = 0; mf < 2; ++mf)
#pragma unroll
    for (int nf = 0; nf < 4; ++nf) {
      int n = wn * 64 + nf * 16 + col;
      int gt = n >> 5, jn = n & 31;
#pragma unroll
      for (int r = 0; r < 4; ++r) {
        int m = wm * 32 + mf * 16 + quad * 4 + r;
        L[(gt * 64 + m) * 32 + jn] = acc[mf][nf][r];
      }
    }
  __syncthreads();

  const int isbf = *flag;
#pragma unroll
  for (int p = 0; p < 8; ++p) {
    int m = p * 8 + (tid >> 5), n = tid & 31;
    float gi = L[(0 * 64 + m) * 32 + n] + bf2f(xgv[p].x);
    float gf = L[(1 * 64 + m) * 32 + n] + bf2f(xgv[p].y);
    float gg = L[(2 * 64 + m) * 32 + n] + bf2f(xgv[p].z);
    float go = L[(3 * 64 + m) * 32 + n] + bf2f(xgv[p].w);
    float si = 1.f / (1.f + __expf(-gi));
    float sf = 1.f / (1.f + __expf(-gf));
    float so = 1.f / (1.f + __expf(-go));
    float cn = sf * cold[p] + si * tanhf(gg);
    float h = so * tanhf(cn);
    int bg = m0 + m, jg = j0 + n;
    cst[((long)d * NB + bg) * NH + jg] = cn;
    if (layer == 0) {
      h0cat[((long)tq * NB + bg) * (2 * NH) + d * NH + jg] = f2bf(h);
    } else {
      hbuf[(t & 1) * (2L * NB * NH) + ((long)d * NB + bg) * NH + jg] = f2bf(h);
      if (qlen[bg] - 1 == tq) {
        long oi = (long)bg * (2 * NH) + d * NH + jg;
        if (isbf)
          ((u16*)outp)[oi] = f2bf(h);
        else
          ((float*)outp)[oi] = h;
      }
    }
  }
}

extern "C" void kernel_launch(void* const* d_in, const int* in_sizes, int n_in,
                              void* d_out, int out_size, void* d_ws,
                              size_t ws_size, hipStream_t stream) {
  const int* qv = (const int*)d_in[0];
  const int* ql = (const int*)d_in[1];
  const void* lookup = d_in[2];
  const void* wih0 = d_in[3];
  const void* whh0 = d_in[4];
  const void* b0 = d_in[5];
  const void* wih1 = d_in[6];
  const void* whh1 = d_in[7];
  const void* b1 = d_in[8];

  char* ws = (char*)d_ws;
  size_t off = 0;
  int* flag = (int*)ws;                 off += 256;
  float* bsum = (float*)(ws + off);     off += 2L * 2 * G4 * 4;        // 32 KB
  u16* Wc0 = (u16*)(ws + off);          off += 2L * G4 * 1024 * 2;     // 8 MB
  u16* Wc1 = (u16*)(ws + off);          off += 2L * G4 * 1536 * 2;     // 12 MB
  u16* hbuf = (u16*)(ws + off);         off += 2L * 2 * NB * NH * 2;   // 2 MB
  float* cbuf = (float*)(ws + off);     off += 2L * NB * NH * 4;       // 2 MB
  u16* h0cat = (u16*)(ws + off);        off += (size_t)NW * NB * 2 * NH * 2; // 40 MB
  u16* emb = (u16*)(ws + off);          off += (size_t)NW * NB * NE * 2;     // 20 MB
  u16* xg = (u16*)(ws + off);           off += (size_t)NW * 2 * 16 * 512 * 128 * 2; // 168 MB
  u16* tableT = h0cat;  // tableT (12.3 MB) aliases h0cat: dead before layer0

  detect_kernel<<<1, 64, 0, stream>>>((const u16*)lookup, flag);
  table_kernel<<<dim3(188, 8), dim3(64, 4), 0, stream>>>(lookup, flag, tableT);
  {
    long total = 2L * G4 * 1024 + 2L * G4 * 1536 + 2L * 2 * G4;
    int blocks = (int)((total + 255) / 256);
    pack_kernel<<<blocks, 256, 0, stream>>>(wih0, whh0, b0, wih1, whh1, b1,
                                            flag, Wc0, Wc1, bsum);
  }
  embed_kernel<<<NW * NB / 4, 256, 0, stream>>>(qv, tableT, emb);

  // layer 0: input-projection GEMM, then 40 per-step kernels
  xg_gemm<<<dim3(160, 32), 256, 0, stream>>>(emb, 512, 1024, Wc0, bsum, xg);
  for (int t = 0; t < NW; ++t)
    hstep<<<256, 256, 0, stream>>>(xg, Wc0, 1024, 512, hbuf, h0cat, d_out, ql,
                                   flag, cbuf, t, 0);
  // layer 1
  xg_gemm<<<dim3(160, 32), 256, 0, stream>>>(h0cat, 1024, 1536, Wc1,
                                             bsum + 2 * G4, xg);
  for (int t = 0; t < NW; ++t)
    hstep<<<256, 256, 0, stream>>>(xg, Wc1, 1536, 1024, hbuf, h0cat, d_out, ql,
                                   flag, cbuf, t, 1);
}

// Round 5
// 1442.990 us; speedup vs baseline: 2.7181x; 1.0039x over previous
//
#include <hip/hip_runtime.h>
#include <hip/hip_bf16.h>
#include <stdint.h>

#define NB 512
#define NW 40
#define NE 512
#define NH 512
#define NV 12000
#define G4 2048

typedef unsigned short u16;
typedef unsigned int u32;
typedef unsigned long long u64;
typedef __attribute__((ext_vector_type(8))) short short8;
typedef __attribute__((ext_vector_type(4))) float f32x4;

__device__ __forceinline__ unsigned short f2bf(float f) {
  unsigned int u = __float_as_uint(f);
  u += 0x7FFF + ((u >> 16) & 1);
  return (unsigned short)(u >> 16);
}
__device__ __forceinline__ float bf2f(unsigned short b) {
  return __uint_as_float(((unsigned int)b) << 16);
}
__device__ __forceinline__ float loadIn(const void* p, long i, int bf) {
  return bf ? bf2f(((const u16*)p)[i]) : ((const float*)p)[i];
}

// ---------------- dtype detector ----------------
__global__ void detect_kernel(const u16* p, int* flag) {
  __shared__ int cnt;
  int i = threadIdx.x;
  if (i == 0) cnt = 0;
  __syncthreads();
  unsigned short u = p[2 * (i * 1001)];
  int e = (u >> 7) & 0xFF;
  if (e >= 100 && e <= 126) atomicAdd(&cnt, 1);
  __syncthreads();
  if (i == 0) *flag = (cnt >= 32) ? 1 : 0;
}

// ---------------- tableT = bf16(tanh(lookup_W^T)), (V, E) ----------------
__global__ void table_kernel(const void* lookup, const int* flag, u16* tableT) {
  __shared__ float tile[64][65];
  int bf = *flag;
  int v0 = blockIdx.x * 64, e0 = blockIdx.y * 64;
  int tx = threadIdx.x, ty = threadIdx.y;  // (64,4)
#pragma unroll
  for (int r = 0; r < 16; ++r) {
    int e = r * 4 + ty, v = tx;
    if (v0 + v < NV)
      tile[e][v] = tanhf(loadIn(lookup, (long)(e0 + e) * NV + v0 + v, bf));
  }
  __syncthreads();
#pragma unroll
  for (int r = 0; r < 16; ++r) {
    int v = r * 4 + ty, e = tx;
    if (v0 + v < NV)
      tableT[(long)(v0 + v) * NE + e0 + e] = f2bf(tile[e][v]);
  }
}

// ---------------- emb (W*B, E) bf16, rows tb = t*NB+b ----------------
__global__ void embed_kernel(const int* __restrict__ qv,
                             const u16* __restrict__ tableT,
                             u16* __restrict__ emb) {
  int tid = blockIdx.x * 256 + threadIdx.x;
  int token = tid >> 6;
  int chunk = tid & 63;
  int tt = token / NB, b = token % NB;
  int q = qv[b * NW + tt];
  uint4 val = make_uint4(0u, 0u, 0u, 0u);
  if (q > 0) val = *(const uint4*)(tableT + (long)(q - 1) * NE + chunk * 8);
  *(uint4*)(emb + (long)token * NE + chunk * 8) = val;
}

// ---------------- pack weights: Wc[d] rows = [wih | whh], bf16 ------------
__global__ void pack_kernel(const void* wih0, const void* whh0, const void* b0,
                            const void* wih1, const void* whh1, const void* b1,
                            const int* flag, u16* Wc0, u16* Wc1, float* bsum) {
  const long N0 = 2L * G4 * 1024, N1 = 2L * G4 * 1536;
  long idx = (long)blockIdx.x * 256 + threadIdx.x;
  int bf = *flag;
  if (idx < N0) {
    int d = (int)(idx / (G4 * 1024));
    int rem = (int)(idx % (long)(G4 * 1024));
    int g = rem / 1024, k = rem % 1024;
    float v = (k < 512) ? loadIn(wih0, ((long)d * G4 + g) * 512 + k, bf)
                        : loadIn(whh0, ((long)d * G4 + g) * 512 + (k - 512), bf);
    Wc0[idx] = f2bf(v);
  } else if (idx < N0 + N1) {
    long i2 = idx - N0;
    int d = (int)(i2 / (G4 * 1536));
    int rem = (int)(i2 % (long)(G4 * 1536));
    int g = rem / 1536, k = rem % 1536;
    float v = (k < 1024) ? loadIn(wih1, ((long)d * G4 + g) * 1024 + k, bf)
                         : loadIn(whh1, ((long)d * G4 + g) * 512 + (k - 1024), bf);
    Wc1[i2] = f2bf(v);
  } else if (idx < N0 + N1 + 2L * 2 * G4) {
    long i3 = idx - N0 - N1;  // [layer][d][g]
    int layer = (int)(i3 / (2 * G4));
    int d = (int)((i3 / G4) & 1);
    int g = (int)(i3 % G4);
    const void* bb = layer ? b1 : b0;
    float v = loadIn(bb, (long)d * 2 * G4 + g, bf) +
              loadIn(bb, (long)d * 2 * G4 + G4 + g, bf);
    bsum[i3] = v;
  }
}

// ---------------- zero the barrier (8 KB) ----------------
__global__ void zero_bar(unsigned int* bar) {
  bar[blockIdx.x * 256 + threadIdx.x] = 0u;
}

// ---------------- xg GEMM: xg[t][d][col][b][jn*4+g] = X@Wih^T + bias ------
// 128x128 tile, BK=64, m97-style staging, 4 waves 2x2. (R4-validated.)
__global__ __launch_bounds__(256, 2) void xg_gemm(
    const u16* __restrict__ X, int Kx, int Kfull, const u16* __restrict__ Wc,
    const float* __restrict__ bsumL, u16* __restrict__ xg) {
  __shared__ __align__(16) char lds[32768];  // A 16K + B 16K
  const int tid = threadIdx.x;
  const int lane = tid & 63, wv = tid >> 6;
  const int wm = wv & 1, wn = wv >> 1;
  const int col = lane & 15, quad = lane >> 4;
  const int tb0 = blockIdx.x * 128;
  const int by = blockIdx.y;
  const int d = by >> 4, colb = by & 15, j0 = colb * 32;

  f32x4 zero = {0.f, 0.f, 0.f, 0.f};
  f32x4 acc[4][4];
#pragma unroll
  for (int i = 0; i < 4; ++i)
#pragma unroll
    for (int j = 0; j < 4; ++j) acc[i][j] = zero;

  const int iters = Kx >> 6;
  for (int it = 0; it < iters; ++it) {
    int k0 = it << 6;
#pragma unroll
    for (int p = 0; p < 8; ++p) {
      int c = p * 256 + tid;  // [0,2048)
      const u16* gsrc;
      if (c < 1024) {  // A rows 0..127
        int r = c >> 3, sl = c & 7;
        int kk = k0 + ((sl * 8) ^ ((r & 7) << 3));
        gsrc = X + (long)(tb0 + r) * Kx + kk;
      } else {
        int cb = c - 1024;
        int r = cb >> 3, sl = cb & 7;
        int kk = k0 + ((sl * 8) ^ ((r & 7) << 3));
        int grow = (r >> 5) * 512 + j0 + (r & 31);
        gsrc = Wc + ((long)d * G4 + grow) * Kfull + kk;
      }
      __builtin_amdgcn_global_load_lds(
          (const __attribute__((address_space(1))) void*)(const void*)gsrc,
          (__attribute__((address_space(3))) void*)(lds + p * 4096 + wv * 1024),
          16, 0, 0);
    }
    __syncthreads();
    const u16* As = (const u16*)lds;
    const u16* Bs = (const u16*)(lds + 16384);
#pragma unroll
    for (int ks = 0; ks < 2; ++ks) {
      short8 afr[4], bfr[4];
#pragma unroll
      for (int mf = 0; mf < 4; ++mf) {
        int rm = wm * 64 + mf * 16 + col;
        int sl = (ks * 32 + quad * 8) ^ ((rm & 7) << 3);
        afr[mf] = *(const short8*)(As + rm * 64 + sl);
      }
#pragma unroll
      for (int nf = 0; nf < 4; ++nf) {
        int br = wn * 64 + nf * 16 + col;
        int sl = (ks * 32 + quad * 8) ^ ((br & 7) << 3);
        bfr[nf] = *(const short8*)(Bs + br * 64 + sl);
      }
#pragma unroll
      for (int mf = 0; mf < 4; ++mf)
#pragma unroll
        for (int nf = 0; nf < 4; ++nf)
          acc[mf][nf] = __builtin_amdgcn_mfma_f32_16x16x32_bf16(
              afr[mf], bfr[nf], acc[mf][nf], 0, 0, 0);
    }
    __syncthreads();
  }

  float bias[4];
#pragma unroll
  for (int nf = 0; nf < 4; ++nf) {
    int n = wn * 64 + nf * 16 + col;
    bias[nf] = bsumL[d * G4 + (n >> 5) * 512 + j0 + (n & 31)];
  }
#pragma unroll
  for (int mf = 0; mf < 4; ++mf)
#pragma unroll
    for (int nf = 0; nf < 4; ++nf) {
      int n = wn * 64 + nf * 16 + col;
      int g = n >> 5, jn = n & 31;
#pragma unroll
      for (int r = 0; r < 4; ++r) {
        int m = wm * 64 + mf * 16 + quad * 4 + r;
        int tb = tb0 + m, t = tb >> 9, b = tb & 511;
        long oi = ((((long)t * 2 + d) * 16 + colb) * 512 + b) * 128 + jn * 4 + g;
        xg[oi] = f2bf(acc[mf][nf][r] + bias[nf]);
      }
    }
}

// ---------------- persistent bidirectional LSTM recurrence ----------------
// One launch per layer. 256 blocks, 1/CU (144 KB LDS). Block = colid x mi:
// 64 batch x (4 gates x 32 j), dir d = colid>>4. Whh slice LDS-resident.
// Cross-block h via RELAXED AGENT atomics (sc0|sc1, data at LLC) -- NO
// fences, NO buffer_wbl2/inv walks (R3's failure mode). Tree barrier with
// relaxed atomics; __syncthreads() drains vmcnt before signaling.
__global__ __launch_bounds__(256, 1) void lstm_pers(
    const u16* __restrict__ xg, const u16* __restrict__ Wc, int Kfull, int Kx,
    u16* __restrict__ hbuf, u16* __restrict__ h0cat, void* __restrict__ outp,
    const int* __restrict__ qlen, const int* __restrict__ flag,
    unsigned int* bar, int layer) {
  __shared__ __align__(16) char lds[147456];  // [Whh 128K][gates 16K]
  const int tid = threadIdx.x;
  const int lane = tid & 63, wv = tid >> 6;
  const int wm = wv & 1, wn = wv >> 1;
  const int col = lane & 15, quad = lane >> 4;
  const int l = blockIdx.x;
  const int colid = l & 31, mi = l >> 5;
  const int colb = colid & 15, j0 = colb * 32, d = colid >> 4;
  const int m0 = mi * 64;

  // ---- preload Whh slice into LDS: rows r=g*32+jn, [128][512] swizzled ----
#pragma unroll
  for (int p = 0; p < 32; ++p) {
    int c = p * 256 + tid;
    int row = c >> 6, rem = c & 63;
    int kc = rem >> 3, sl = rem & 7;
    int grow = (row >> 5) * 512 + j0 + (row & 31);
    int gk = Kx + kc * 64 + ((sl * 8) ^ ((row & 7) << 3));
    const u16* gsrc = Wc + ((long)d * G4 + grow) * Kfull + gk;
    __builtin_amdgcn_global_load_lds(
        (const __attribute__((address_space(1))) void*)(const void*)gsrc,
        (__attribute__((address_space(3))) void*)(lds + p * 4096 + wv * 1024),
        16, 0, 0);
  }
  __syncthreads();
  const u16* Bs = (const u16*)lds;
  float* GL = (float*)(lds + 131072);  // [2][64][32] fp32

  // epilogue pair mapping: u = tid&15 -> n0 = 2u; mr = tid>>4; m = p*16+mr
  const int eu = tid & 15, emr = tid >> 4;
  float creg[4][2];
#pragma unroll
  for (int p = 0; p < 4; ++p) creg[p][0] = creg[p][1] = 0.f;
  const int isbf = *flag;
  f32x4 zero = {0.f, 0.f, 0.f, 0.f};

#pragma unroll 1
  for (int t = 0; t < NW; ++t) {
    const int tq = d ? (NW - 1 - t) : t;
    // xg prefetch (plain loads, immutable input): one ushort8 per p
    uint4 xgv[4];
    const u16* xgt = xg + ((((long)tq * 2 + d) * 16 + colb) * 512 + m0) * 128;
#pragma unroll
    for (int p = 0; p < 4; ++p) {
      int m = p * 16 + emr;
      xgv[p] = *(const uint4*)(xgt + m * 128 + eu * 8);
    }

    f32x4 acc[2][4];
#pragma unroll
    for (int i = 0; i < 2; ++i)
#pragma unroll
      for (int j = 0; j < 4; ++j) acc[i][j] = zero;

    if (t > 0) {
      const u16* hp =
          hbuf + ((t - 1) & 1) * (2L * NB * NH) + (long)d * NB * NH;
      // software-pipelined sc1 h loads, depth 4 (32 outstanding 8B loads)
      u64 hv[4][2][2][2];
#pragma unroll
      for (int pf = 0; pf < 4; ++pf) {
#pragma unroll
        for (int ks = 0; ks < 2; ++ks)
#pragma unroll
          for (int mf = 0; mf < 2; ++mf) {
            const u16* a = hp + (long)(m0 + wm * 32 + mf * 16 + col) * NH +
                           pf * 64 + ks * 32 + quad * 8;
            hv[pf][ks][mf][0] = __hip_atomic_load(
                (const u64*)a, __ATOMIC_RELAXED, __HIP_MEMORY_SCOPE_AGENT);
            hv[pf][ks][mf][1] = __hip_atomic_load(
                (const u64*)(a + 4), __ATOMIC_RELAXED, __HIP_MEMORY_SCOPE_AGENT);
          }
      }
#pragma unroll
      for (int it = 0; it < 8; ++it) {
        const int b = it & 3;
#pragma unroll
        for (int ks = 0; ks < 2; ++ks) {
          short8 afr[2], bfr[4];
#pragma unroll
          for (int mf = 0; mf < 2; ++mf) {
            ((u64*)&afr[mf])[0] = hv[b][ks][mf][0];
            ((u64*)&afr[mf])[1] = hv[b][ks][mf][1];
          }
#pragma unroll
          for (int nf = 0; nf < 4; ++nf) {
            int br = wn * 64 + nf * 16 + col;
            int sl = (ks * 32 + quad * 8) ^ ((br & 7) << 3);
            bfr[nf] = *(const short8*)(Bs + br * 512 + it * 64 + sl);
          }
#pragma unroll
          for (int mf = 0; mf < 2; ++mf)
#pragma unroll
            for (int nf = 0; nf < 4; ++nf)
              acc[mf][nf] = __builtin_amdgcn_mfma_f32_16x16x32_bf16(
                  afr[mf], bfr[nf], acc[mf][nf], 0, 0, 0);
        }
        if (it + 4 < 8) {
          const int pf = it + 4;
#pragma unroll
          for (int ks = 0; ks < 2; ++ks)
#pragma unroll
            for (int mf = 0; mf < 2; ++mf) {
              const u16* a = hp + (long)(m0 + wm * 32 + mf * 16 + col) * NH +
                             pf * 64 + ks * 32 + quad * 8;
              hv[b][ks][mf][0] = __hip_atomic_load(
                  (const u64*)a, __ATOMIC_RELAXED, __HIP_MEMORY_SCOPE_AGENT);
              hv[b][ks][mf][1] =
                  __hip_atomic_load((const u64*)(a + 4), __ATOMIC_RELAXED,
                                    __HIP_MEMORY_SCOPE_AGENT);
            }
        }
      }
    }

    // ---- two-phase gate exchange (R3-verified layout) ----
    if (wn == 0) {  // gates 0(i),1(f)
#pragma unroll
      for (int mf = 0; mf < 2; ++mf)
#pragma unroll
        for (int nf = 0; nf < 4; ++nf) {
          int n = nf * 16 + col;
#pragma unroll
          for (int r = 0; r < 4; ++r) {
            int m = wm * 32 + mf * 16 + quad * 4 + r;
            GL[((n >> 5) * 64 + m) * 32 + (n & 31)] = acc[mf][nf][r];
          }
        }
    }
    __syncthreads();
    float si[4][2], sf[4][2];
#pragma unroll
    for (int p = 0; p < 4; ++p) {
      int m = p * 16 + emr, n0 = eu * 2;
      const u16* xv = (const u16*)&xgv[p];
#pragma unroll
      for (int q = 0; q < 2; ++q) {
        float gi = GL[(0 * 64 + m) * 32 + n0 + q] + bf2f(xv[q * 4 + 0]);
        float gf = GL[(1 * 64 + m) * 32 + n0 + q] + bf2f(xv[q * 4 + 1]);
        si[p][q] = 1.f / (1.f + __expf(-gi));
        sf[p][q] = 1.f / (1.f + __expf(-gf));
      }
    }
    __syncthreads();
    if (wn == 1) {  // gates 2(g),3(o)
#pragma unroll
      for (int mf = 0; mf < 2; ++mf)
#pragma unroll
        for (int nf = 0; nf < 4; ++nf) {
          int n = 64 + nf * 16 + col;
#pragma unroll
          for (int r = 0; r < 4; ++r) {
            int m = wm * 32 + mf * 16 + quad * 4 + r;
            GL[(((n >> 5) - 2) * 64 + m) * 32 + (n & 31)] = acc[mf][nf][r];
          }
        }
    }
    __syncthreads();
    u16* hnxt = hbuf + (t & 1) * (2L * NB * NH);
#pragma unroll
    for (int p = 0; p < 4; ++p) {
      int m = p * 16 + emr, n0 = eu * 2;
      const u16* xv = (const u16*)&xgv[p];
      float hh[2];
#pragma unroll
      for (int q = 0; q < 2; ++q) {
        float gg = GL[(0 * 64 + m) * 32 + n0 + q] + bf2f(xv[q * 4 + 2]);
        float go = GL[(1 * 64 + m) * 32 + n0 + q] + bf2f(xv[q * 4 + 3]);
        float cn = sf[p][q] * creg[p][q] + si[p][q] * tanhf(gg);
        float so = 1.f / (1.f + __expf(-go));
        hh[q] = so * tanhf(cn);
        creg[p][q] = cn;
      }
      int bg = m0 + m, jg = j0 + n0;
      unsigned hw = (unsigned)f2bf(hh[0]) | ((unsigned)f2bf(hh[1]) << 16);
      // recurrence copy: sc1 store (visible at LLC, no fence needed)
      __hip_atomic_store((u32*)(hnxt + ((long)d * NB + bg) * NH + jg), hw,
                         __ATOMIC_RELAXED, __HIP_MEMORY_SCOPE_AGENT);
      if (layer == 0) {
        // plain store; flushed at kernel end for the next xg_gemm
        *(u32*)(h0cat + ((long)tq * NB + bg) * (2 * NH) + d * NH + jg) = hw;
      } else if (qlen[bg] - 1 == tq) {
        long oi = (long)bg * (2 * NH) + d * NH + jg;
        if (isbf)
          *(u32*)((u16*)outp + oi) = hw;
        else {
          ((float*)outp)[oi] = hh[0];
          ((float*)outp)[oi + 1] = hh[1];
        }
      }
    }

    // ---- tree barrier, relaxed agent atomics only ----
    if (t < NW - 1) {
      __syncthreads();  // drains each thread's vmcnt (sc1 stores at LLC)
      if (tid == 0) {
        unsigned lv = __hip_atomic_fetch_add(&bar[(l & 7) * 64], 1u,
                                             __ATOMIC_RELAXED,
                                             __HIP_MEMORY_SCOPE_AGENT);
        if (lv == 32u * (t + 1) - 1u) {
          unsigned rv = __hip_atomic_fetch_add(
              &bar[1024], 1u, __ATOMIC_RELAXED, __HIP_MEMORY_SCOPE_AGENT);
          if (rv == 8u * (t + 1) - 1u)
            __hip_atomic_store(&bar[1088], (unsigned)(t + 1), __ATOMIC_RELAXED,
                               __HIP_MEMORY_SCOPE_AGENT);
        }
        while (__hip_atomic_load(&bar[1088], __ATOMIC_RELAXED,
                                 __HIP_MEMORY_SCOPE_AGENT) < (unsigned)(t + 1))
          __builtin_amdgcn_s_sleep(1);
      }
      __syncthreads();
    }
  }
}

extern "C" void kernel_launch(void* const* d_in, const int* in_sizes, int n_in,
                              void* d_out, int out_size, void* d_ws,
                              size_t ws_size, hipStream_t stream) {
  const int* qv = (const int*)d_in[0];
  const int* ql = (const int*)d_in[1];
  const void* lookup = d_in[2];
  const void* wih0 = d_in[3];
  const void* whh0 = d_in[4];
  const void* b0 = d_in[5];
  const void* wih1 = d_in[6];
  const void* whh1 = d_in[7];
  const void* b1 = d_in[8];

  char* ws = (char*)d_ws;
  size_t off = 0;
  int* flag = (int*)ws;                 off += 256;
  unsigned int* bar = (unsigned int*)(ws + off); off += 8192;
  float* bsum = (float*)(ws + off);     off += 2L * 2 * G4 * 4;        // 32 KB
  u16* Wc0 = (u16*)(ws + off);          off += 2L * G4 * 1024 * 2;     // 8 MB
  u16* Wc1 = (u16*)(ws + off);          off += 2L * G4 * 1536 * 2;     // 12 MB
  u16* hbuf = (u16*)(ws + off);         off += 2L * 2 * NB * NH * 2;   // 2 MB
  u16* h0cat = (u16*)(ws + off);        off += (size_t)NW * NB * 2 * NH * 2; // 40 MB
  u16* emb = (u16*)(ws + off);          off += (size_t)NW * NB * NE * 2;     // 20 MB
  u16* xg = (u16*)(ws + off);           off += (size_t)NW * 2 * 16 * 512 * 128 * 2; // 168 MB
  u16* tableT = h0cat;  // tableT (12.3 MB) aliases h0cat: dead before layer0

  detect_kernel<<<1, 64, 0, stream>>>((const u16*)lookup, flag);
  table_kernel<<<dim3(188, 8), dim3(64, 4), 0, stream>>>(lookup, flag, tableT);
  {
    long total = 2L * G4 * 1024 + 2L * G4 * 1536 + 2L * 2 * G4;
    int blocks = (int)((total + 255) / 256);
    pack_kernel<<<blocks, 256, 0, stream>>>(wih0, whh0, b0, wih1, whh1, b1,
                                            flag, Wc0, Wc1, bsum);
  }
  embed_kernel<<<NW * NB / 4, 256, 0, stream>>>(qv, tableT, emb);

  // layer 0
  xg_gemm<<<dim3(160, 32), 256, 0, stream>>>(emb, 512, 1024, Wc0, bsum, xg);
  zero_bar<<<8, 256, 0, stream>>>(bar);
  lstm_pers<<<256, 256, 0, stream>>>(xg, Wc0, 1024, 512, hbuf, h0cat, d_out,
                                     ql, flag, bar, 0);
  // layer 1
  xg_gemm<<<dim3(160, 32), 256, 0, stream>>>(h0cat, 1024, 1536, Wc1,
                                             bsum + 2 * G4, xg);
  zero_bar<<<8, 256, 0, stream>>>(bar);
  lstm_pers<<<256, 256, 0, stream>>>(xg, Wc1, 1536, 1024, hbuf, h0cat, d_out,
                                     ql, flag, bar, 1);
}

// Round 6
// 1346.389 us; speedup vs baseline: 2.9131x; 1.0717x over previous
//
#include <hip/hip_runtime.h>
#include <hip/hip_bf16.h>
#include <stdint.h>

#define NB 512
#define NW 40
#define NE 512
#define NH 512
#define NV 12000
#define G4 2048

typedef unsigned short u16;
typedef unsigned int u32;
typedef unsigned long long u64;
typedef __attribute__((ext_vector_type(8))) short short8;
typedef __attribute__((ext_vector_type(4))) float f32x4;

__device__ __forceinline__ unsigned short f2bf(float f) {
  unsigned int u = __float_as_uint(f);
  u += 0x7FFF + ((u >> 16) & 1);
  return (unsigned short)(u >> 16);
}
__device__ __forceinline__ float bf2f(unsigned short b) {
  return __uint_as_float(((unsigned int)b) << 16);
}
__device__ __forceinline__ float loadIn(const void* p, long i, int bf) {
  return bf ? bf2f(((const u16*)p)[i]) : ((const float*)p)[i];
}

// ---------------- dtype detector ----------------
__global__ void detect_kernel(const u16* p, int* flag) {
  __shared__ int cnt;
  int i = threadIdx.x;
  if (i == 0) cnt = 0;
  __syncthreads();
  unsigned short u = p[2 * (i * 1001)];
  int e = (u >> 7) & 0xFF;
  if (e >= 100 && e <= 126) atomicAdd(&cnt, 1);
  __syncthreads();
  if (i == 0) *flag = (cnt >= 32) ? 1 : 0;
}

// ---------------- tableT = bf16(tanh(lookup_W^T)), (V, E) ----------------
__global__ void table_kernel(const void* lookup, const int* flag, u16* tableT) {
  __shared__ float tile[64][65];
  int bf = *flag;
  int v0 = blockIdx.x * 64, e0 = blockIdx.y * 64;
  int tx = threadIdx.x, ty = threadIdx.y;  // (64,4)
#pragma unroll
  for (int r = 0; r < 16; ++r) {
    int e = r * 4 + ty, v = tx;
    if (v0 + v < NV)
      tile[e][v] = tanhf(loadIn(lookup, (long)(e0 + e) * NV + v0 + v, bf));
  }
  __syncthreads();
#pragma unroll
  for (int r = 0; r < 16; ++r) {
    int v = r * 4 + ty, e = tx;
    if (v0 + v < NV)
      tableT[(long)(v0 + v) * NE + e0 + e] = f2bf(tile[e][v]);
  }
}

// ---------------- emb (W*B, E) bf16, rows tb = t*NB+b ----------------
__global__ void embed_kernel(const int* __restrict__ qv,
                             const u16* __restrict__ tableT,
                             u16* __restrict__ emb) {
  int tid = blockIdx.x * 256 + threadIdx.x;
  int token = tid >> 6;
  int chunk = tid & 63;
  int tt = token / NB, b = token % NB;
  int q = qv[b * NW + tt];
  uint4 val = make_uint4(0u, 0u, 0u, 0u);
  if (q > 0) val = *(const uint4*)(tableT + (long)(q - 1) * NE + chunk * 8);
  *(uint4*)(emb + (long)token * NE + chunk * 8) = val;
}

// ---------------- pack weights: Wc[d] rows = [wih | whh], bf16 ------------
__global__ void pack_kernel(const void* wih0, const void* whh0, const void* b0,
                            const void* wih1, const void* whh1, const void* b1,
                            const int* flag, u16* Wc0, u16* Wc1, float* bsum) {
  const long N0 = 2L * G4 * 1024, N1 = 2L * G4 * 1536;
  long idx = (long)blockIdx.x * 256 + threadIdx.x;
  int bf = *flag;
  if (idx < N0) {
    int d = (int)(idx / (G4 * 1024));
    int rem = (int)(idx % (long)(G4 * 1024));
    int g = rem / 1024, k = rem % 1024;
    float v = (k < 512) ? loadIn(wih0, ((long)d * G4 + g) * 512 + k, bf)
                        : loadIn(whh0, ((long)d * G4 + g) * 512 + (k - 512), bf);
    Wc0[idx] = f2bf(v);
  } else if (idx < N0 + N1) {
    long i2 = idx - N0;
    int d = (int)(i2 / (G4 * 1536));
    int rem = (int)(i2 % (long)(G4 * 1536));
    int g = rem / 1536, k = rem % 1536;
    float v = (k < 1024) ? loadIn(wih1, ((long)d * G4 + g) * 1024 + k, bf)
                         : loadIn(whh1, ((long)d * G4 + g) * 512 + (k - 1024), bf);
    Wc1[i2] = f2bf(v);
  } else if (idx < N0 + N1 + 2L * 2 * G4) {
    long i3 = idx - N0 - N1;  // [layer][d][g]
    int layer = (int)(i3 / (2 * G4));
    int d = (int)((i3 / G4) & 1);
    int g = (int)(i3 % G4);
    const void* bb = layer ? b1 : b0;
    float v = loadIn(bb, (long)d * 2 * G4 + g, bf) +
              loadIn(bb, (long)d * 2 * G4 + G4 + g, bf);
    bsum[i3] = v;
  }
}

// ---------------- zero the barrier (8 KB) ----------------
__global__ void zero_bar(unsigned int* bar) {
  bar[blockIdx.x * 256 + threadIdx.x] = 0u;
}

// ---------------- xg GEMM: xg[t][d][col][b][jn*4+g] = X@Wih^T + bias ------
// 128x128 tile, BK=64, m97-style staging, 4 waves 2x2. (R4-validated.)
__global__ __launch_bounds__(256, 2) void xg_gemm(
    const u16* __restrict__ X, int Kx, int Kfull, const u16* __restrict__ Wc,
    const float* __restrict__ bsumL, u16* __restrict__ xg) {
  __shared__ __align__(16) char lds[32768];  // A 16K + B 16K
  const int tid = threadIdx.x;
  const int lane = tid & 63, wv = tid >> 6;
  const int wm = wv & 1, wn = wv >> 1;
  const int col = lane & 15, quad = lane >> 4;
  const int tb0 = blockIdx.x * 128;
  const int by = blockIdx.y;
  const int d = by >> 4, colb = by & 15, j0 = colb * 32;

  f32x4 zero = {0.f, 0.f, 0.f, 0.f};
  f32x4 acc[4][4];
#pragma unroll
  for (int i = 0; i < 4; ++i)
#pragma unroll
    for (int j = 0; j < 4; ++j) acc[i][j] = zero;

  const int iters = Kx >> 6;
  for (int it = 0; it < iters; ++it) {
    int k0 = it << 6;
#pragma unroll
    for (int p = 0; p < 8; ++p) {
      int c = p * 256 + tid;  // [0,2048)
      const u16* gsrc;
      if (c < 1024) {  // A rows 0..127
        int r = c >> 3, sl = c & 7;
        int kk = k0 + ((sl * 8) ^ ((r & 7) << 3));
        gsrc = X + (long)(tb0 + r) * Kx + kk;
      } else {
        int cb = c - 1024;
        int r = cb >> 3, sl = cb & 7;
        int kk = k0 + ((sl * 8) ^ ((r & 7) << 3));
        int grow = (r >> 5) * 512 + j0 + (r & 31);
        gsrc = Wc + ((long)d * G4 + grow) * Kfull + kk;
      }
      __builtin_amdgcn_global_load_lds(
          (const __attribute__((address_space(1))) void*)(const void*)gsrc,
          (__attribute__((address_space(3))) void*)(lds + p * 4096 + wv * 1024),
          16, 0, 0);
    }
    __syncthreads();
    const u16* As = (const u16*)lds;
    const u16* Bs = (const u16*)(lds + 16384);
#pragma unroll
    for (int ks = 0; ks < 2; ++ks) {
      short8 afr[4], bfr[4];
#pragma unroll
      for (int mf = 0; mf < 4; ++mf) {
        int rm = wm * 64 + mf * 16 + col;
        int sl = (ks * 32 + quad * 8) ^ ((rm & 7) << 3);
        afr[mf] = *(const short8*)(As + rm * 64 + sl);
      }
#pragma unroll
      for (int nf = 0; nf < 4; ++nf) {
        int br = wn * 64 + nf * 16 + col;
        int sl = (ks * 32 + quad * 8) ^ ((br & 7) << 3);
        bfr[nf] = *(const short8*)(Bs + br * 64 + sl);
      }
#pragma unroll
      for (int mf = 0; mf < 4; ++mf)
#pragma unroll
        for (int nf = 0; nf < 4; ++nf)
          acc[mf][nf] = __builtin_amdgcn_mfma_f32_16x16x32_bf16(
              afr[mf], bfr[nf], acc[mf][nf], 0, 0, 0);
    }
    __syncthreads();
  }

  float bias[4];
#pragma unroll
  for (int nf = 0; nf < 4; ++nf) {
    int n = wn * 64 + nf * 16 + col;
    bias[nf] = bsumL[d * G4 + (n >> 5) * 512 + j0 + (n & 31)];
  }
#pragma unroll
  for (int mf = 0; mf < 4; ++mf)
#pragma unroll
    for (int nf = 0; nf < 4; ++nf) {
      int n = wn * 64 + nf * 16 + col;
      int g = n >> 5, jn = n & 31;
#pragma unroll
      for (int r = 0; r < 4; ++r) {
        int m = wm * 64 + mf * 16 + quad * 4 + r;
        int tb = tb0 + m, t = tb >> 9, b = tb & 511;
        long oi = ((((long)t * 2 + d) * 16 + colb) * 512 + b) * 128 + jn * 4 + g;
        xg[oi] = f2bf(acc[mf][nf][r] + bias[nf]);
      }
    }
}

// ---------------- persistent bidirectional LSTM recurrence ----------------
// One launch per layer. 256 blocks, 1/CU (144 KB LDS). Block = colid x mi:
// 64 batch x (4 gates x 32 j), dir d = colid>>4. Whh slice LDS-resident.
// Cross-block h via relaxed agent atomics (LLC), NO fences (R5-validated).
// R6: (1) per-(mi,d) GROUP barrier -- the 16 blocks sharing (mi,d) are a
// closed system (each block reads h rows mi*64..+64 = exactly what the
// group writes), so a 16-block barrier replaces the 256-block one.
// (2) xg for step t+1 prefetched into registers BEFORE the barrier.
__global__ __launch_bounds__(256, 1) void lstm_pers(
    const u16* __restrict__ xg, const u16* __restrict__ Wc, int Kfull, int Kx,
    u16* __restrict__ hbuf, u16* __restrict__ h0cat, void* __restrict__ outp,
    const int* __restrict__ qlen, const int* __restrict__ flag,
    unsigned int* bar, int layer) {
  __shared__ __align__(16) char lds[147456];  // [Whh 128K][gates 16K]
  const int tid = threadIdx.x;
  const int lane = tid & 63, wv = tid >> 6;
  const int wm = wv & 1, wn = wv >> 1;
  const int col = lane & 15, quad = lane >> 4;
  const int l = blockIdx.x;
  const int colid = l & 31, mi = l >> 5;
  const int colb = colid & 15, j0 = colb * 32, d = colid >> 4;
  const int m0 = mi * 64;
  const int gid = l >> 4;  // == mi*2 + d (16 groups of 16 blocks)

  // ---- preload Whh slice into LDS: rows r=g*32+jn, [128][512] swizzled ----
#pragma unroll
  for (int p = 0; p < 32; ++p) {
    int c = p * 256 + tid;
    int row = c >> 6, rem = c & 63;
    int kc = rem >> 3, sl = rem & 7;
    int grow = (row >> 5) * 512 + j0 + (row & 31);
    int gk = Kx + kc * 64 + ((sl * 8) ^ ((row & 7) << 3));
    const u16* gsrc = Wc + ((long)d * G4 + grow) * Kfull + gk;
    __builtin_amdgcn_global_load_lds(
        (const __attribute__((address_space(1))) void*)(const void*)gsrc,
        (__attribute__((address_space(3))) void*)(lds + p * 4096 + wv * 1024),
        16, 0, 0);
  }
  const u16* Bs = (const u16*)lds;
  float* GL = (float*)(lds + 131072);  // [2][64][32] fp32

  // epilogue pair mapping: u = tid&15 -> n0 = 2u; mr = tid>>4; m = p*16+mr
  const int eu = tid & 15, emr = tid >> 4;
  float creg[4][2];
#pragma unroll
  for (int p = 0; p < 4; ++p) creg[p][0] = creg[p][1] = 0.f;
  const int isbf = *flag;
  f32x4 zero = {0.f, 0.f, 0.f, 0.f};

  // initial xg prefetch for t=0 (overlaps Whh LDS preload)
  uint4 xgv[4], xgn[4];
  {
    const int tq0 = d ? (NW - 1) : 0;
    const u16* xgt = xg + ((((long)tq0 * 2 + d) * 16 + colb) * 512 + m0) * 128;
#pragma unroll
    for (int p = 0; p < 4; ++p)
      xgv[p] = *(const uint4*)(xgt + (p * 16 + emr) * 128 + eu * 8);
  }
  __syncthreads();

#pragma unroll 1
  for (int t = 0; t < NW; ++t) {
    const int tq = d ? (NW - 1 - t) : t;

    f32x4 acc[2][4];
#pragma unroll
    for (int i = 0; i < 2; ++i)
#pragma unroll
      for (int j = 0; j < 4; ++j) acc[i][j] = zero;

    if (t > 0) {
      const u16* hp =
          hbuf + ((t - 1) & 1) * (2L * NB * NH) + (long)d * NB * NH;
      // software-pipelined sc1 h loads, depth 4 (32 outstanding 8B loads)
      u64 hv[4][2][2][2];
#pragma unroll
      for (int pf = 0; pf < 4; ++pf) {
#pragma unroll
        for (int ks = 0; ks < 2; ++ks)
#pragma unroll
          for (int mf = 0; mf < 2; ++mf) {
            const u16* a = hp + (long)(m0 + wm * 32 + mf * 16 + col) * NH +
                           pf * 64 + ks * 32 + quad * 8;
            hv[pf][ks][mf][0] = __hip_atomic_load(
                (const u64*)a, __ATOMIC_RELAXED, __HIP_MEMORY_SCOPE_AGENT);
            hv[pf][ks][mf][1] = __hip_atomic_load(
                (const u64*)(a + 4), __ATOMIC_RELAXED, __HIP_MEMORY_SCOPE_AGENT);
          }
      }
#pragma unroll
      for (int it = 0; it < 8; ++it) {
        const int b = it & 3;
#pragma unroll
        for (int ks = 0; ks < 2; ++ks) {
          short8 afr[2], bfr[4];
#pragma unroll
          for (int mf = 0; mf < 2; ++mf) {
            ((u64*)&afr[mf])[0] = hv[b][ks][mf][0];
            ((u64*)&afr[mf])[1] = hv[b][ks][mf][1];
          }
#pragma unroll
          for (int nf = 0; nf < 4; ++nf) {
            int br = wn * 64 + nf * 16 + col;
            int sl = (ks * 32 + quad * 8) ^ ((br & 7) << 3);
            bfr[nf] = *(const short8*)(Bs + br * 512 + it * 64 + sl);
          }
#pragma unroll
          for (int mf = 0; mf < 2; ++mf)
#pragma unroll
            for (int nf = 0; nf < 4; ++nf)
              acc[mf][nf] = __builtin_amdgcn_mfma_f32_16x16x32_bf16(
                  afr[mf], bfr[nf], acc[mf][nf], 0, 0, 0);
        }
        if (it + 4 < 8) {
          const int pf = it + 4;
#pragma unroll
          for (int ks = 0; ks < 2; ++ks)
#pragma unroll
            for (int mf = 0; mf < 2; ++mf) {
              const u16* a = hp + (long)(m0 + wm * 32 + mf * 16 + col) * NH +
                             pf * 64 + ks * 32 + quad * 8;
              hv[b][ks][mf][0] = __hip_atomic_load(
                  (const u64*)a, __ATOMIC_RELAXED, __HIP_MEMORY_SCOPE_AGENT);
              hv[b][ks][mf][1] =
                  __hip_atomic_load((const u64*)(a + 4), __ATOMIC_RELAXED,
                                    __HIP_MEMORY_SCOPE_AGENT);
            }
        }
      }
    }

    // ---- two-phase gate exchange (R3-verified layout) ----
    if (wn == 0) {  // gates 0(i),1(f)
#pragma unroll
      for (int mf = 0; mf < 2; ++mf)
#pragma unroll
        for (int nf = 0; nf < 4; ++nf) {
          int n = nf * 16 + col;
#pragma unroll
          for (int r = 0; r < 4; ++r) {
            int m = wm * 32 + mf * 16 + quad * 4 + r;
            GL[((n >> 5) * 64 + m) * 32 + (n & 31)] = acc[mf][nf][r];
          }
        }
    }
    __syncthreads();
    float si[4][2], sf[4][2];
#pragma unroll
    for (int p = 0; p < 4; ++p) {
      int m = p * 16 + emr, n0 = eu * 2;
      const u16* xv = (const u16*)&xgv[p];
#pragma unroll
      for (int q = 0; q < 2; ++q) {
        float gi = GL[(0 * 64 + m) * 32 + n0 + q] + bf2f(xv[q * 4 + 0]);
        float gf = GL[(1 * 64 + m) * 32 + n0 + q] + bf2f(xv[q * 4 + 1]);
        si[p][q] = 1.f / (1.f + __expf(-gi));
        sf[p][q] = 1.f / (1.f + __expf(-gf));
      }
    }
    __syncthreads();
    if (wn == 1) {  // gates 2(g),3(o)
#pragma unroll
      for (int mf = 0; mf < 2; ++mf)
#pragma unroll
        for (int nf = 0; nf < 4; ++nf) {
          int n = 64 + nf * 16 + col;
#pragma unroll
          for (int r = 0; r < 4; ++r) {
            int m = wm * 32 + mf * 16 + quad * 4 + r;
            GL[(((n >> 5) - 2) * 64 + m) * 32 + (n & 31)] = acc[mf][nf][r];
          }
        }
    }
    __syncthreads();
    u16* hnxt = hbuf + (t & 1) * (2L * NB * NH);
#pragma unroll
    for (int p = 0; p < 4; ++p) {
      int m = p * 16 + emr, n0 = eu * 2;
      const u16* xv = (const u16*)&xgv[p];
      float hh[2];
#pragma unroll
      for (int q = 0; q < 2; ++q) {
        float gg = GL[(0 * 64 + m) * 32 + n0 + q] + bf2f(xv[q * 4 + 2]);
        float go = GL[(1 * 64 + m) * 32 + n0 + q] + bf2f(xv[q * 4 + 3]);
        float cn = sf[p][q] * creg[p][q] + si[p][q] * tanhf(gg);
        float so = 1.f / (1.f + __expf(-go));
        hh[q] = so * tanhf(cn);
        creg[p][q] = cn;
      }
      int bg = m0 + m, jg = j0 + n0;
      unsigned hw = (unsigned)f2bf(hh[0]) | ((unsigned)f2bf(hh[1]) << 16);
      // recurrence copy: sc1 store (visible at LLC, no fence needed)
      __hip_atomic_store((u32*)(hnxt + ((long)d * NB + bg) * NH + jg), hw,
                         __ATOMIC_RELAXED, __HIP_MEMORY_SCOPE_AGENT);
      if (layer == 0) {
        // plain store; flushed at kernel end for the next xg_gemm
        *(u32*)(h0cat + ((long)tq * NB + bg) * (2 * NH) + d * NH + jg) = hw;
      } else if (qlen[bg] - 1 == tq) {
        long oi = (long)bg * (2 * NH) + d * NH + jg;
        if (isbf)
          *(u32*)((u16*)outp + oi) = hw;
        else {
          ((float*)outp)[oi] = hh[0];
          ((float*)outp)[oi + 1] = hh[1];
        }
      }
    }

    // ---- group barrier (16 blocks sharing (mi,d)), relaxed agent atomics --
    if (t < NW - 1) {
      // prefetch next step's xg BEFORE arriving: HBM latency overlaps wait
      {
        const int tqn = d ? (NW - 2 - t) : (t + 1);
        const u16* xgt =
            xg + ((((long)tqn * 2 + d) * 16 + colb) * 512 + m0) * 128;
#pragma unroll
        for (int p = 0; p < 4; ++p)
          xgn[p] = *(const uint4*)(xgt + (p * 16 + emr) * 128 + eu * 8);
      }
      __syncthreads();  // drains each thread's vmcnt (sc1 stores at LLC)
      if (tid == 0) {
        u32* cnt = &bar[gid * 64];
        u32* flg = &bar[1024 + gid * 64];
        unsigned old = __hip_atomic_fetch_add(cnt, 1u, __ATOMIC_RELAXED,
                                              __HIP_MEMORY_SCOPE_AGENT);
        if (old == 16u * (t + 1) - 1u)
          __hip_atomic_store(flg, (unsigned)(t + 1), __ATOMIC_RELAXED,
                             __HIP_MEMORY_SCOPE_AGENT);
        else
          while (__hip_atomic_load(flg, __ATOMIC_RELAXED,
                                   __HIP_MEMORY_SCOPE_AGENT) <
                 (unsigned)(t + 1))
            __builtin_amdgcn_s_sleep(1);
      }
      __syncthreads();
#pragma unroll
      for (int p = 0; p < 4; ++p) xgv[p] = xgn[p];
    }
  }
}

extern "C" void kernel_launch(void* const* d_in, const int* in_sizes, int n_in,
                              void* d_out, int out_size, void* d_ws,
                              size_t ws_size, hipStream_t stream) {
  const int* qv = (const int*)d_in[0];
  const int* ql = (const int*)d_in[1];
  const void* lookup = d_in[2];
  const void* wih0 = d_in[3];
  const void* whh0 = d_in[4];
  const void* b0 = d_in[5];
  const void* wih1 = d_in[6];
  const void* whh1 = d_in[7];
  const void* b1 = d_in[8];

  char* ws = (char*)d_ws;
  size_t off = 0;
  int* flag = (int*)ws;                 off += 256;
  unsigned int* bar = (unsigned int*)(ws + off); off += 8192;
  float* bsum = (float*)(ws + off);     off += 2L * 2 * G4 * 4;        // 32 KB
  u16* Wc0 = (u16*)(ws + off);          off += 2L * G4 * 1024 * 2;     // 8 MB
  u16* Wc1 = (u16*)(ws + off);          off += 2L * G4 * 1536 * 2;     // 12 MB
  u16* hbuf = (u16*)(ws + off);         off += 2L * 2 * NB * NH * 2;   // 2 MB
  u16* h0cat = (u16*)(ws + off);        off += (size_t)NW * NB * 2 * NH * 2; // 40 MB
  u16* emb = (u16*)(ws + off);          off += (size_t)NW * NB * NE * 2;     // 20 MB
  u16* xg = (u16*)(ws + off);           off += (size_t)NW * 2 * 16 * 512 * 128 * 2; // 168 MB
  u16* tableT = h0cat;  // tableT (12.3 MB) aliases h0cat: dead before layer0

  detect_kernel<<<1, 64, 0, stream>>>((const u16*)lookup, flag);
  table_kernel<<<dim3(188, 8), dim3(64, 4), 0, stream>>>(lookup, flag, tableT);
  {
    long total = 2L * G4 * 1024 + 2L * G4 * 1536 + 2L * 2 * G4;
    int blocks = (int)((total + 255) / 256);
    pack_kernel<<<blocks, 256, 0, stream>>>(wih0, whh0, b0, wih1, whh1, b1,
                                            flag, Wc0, Wc1, bsum);
  }
  embed_kernel<<<NW * NB / 4, 256, 0, stream>>>(qv, tableT, emb);

  // layer 0
  xg_gemm<<<dim3(160, 32), 256, 0, stream>>>(emb, 512, 1024, Wc0, bsum, xg);
  zero_bar<<<8, 256, 0, stream>>>(bar);
  lstm_pers<<<256, 256, 0, stream>>>(xg, Wc0, 1024, 512, hbuf, h0cat, d_out,
                                     ql, flag, bar, 0);
  // layer 1
  xg_gemm<<<dim3(160, 32), 256, 0, stream>>>(h0cat, 1024, 1536, Wc1,
                                             bsum + 2 * G4, xg);
  zero_bar<<<8, 256, 0, stream>>>(bar);
  lstm_pers<<<256, 256, 0, stream>>>(xg, Wc1, 1536, 1024, hbuf, h0cat, d_out,
                                     ql, flag, bar, 1);
}

// Round 7
// 1016.802 us; speedup vs baseline: 3.8573x; 1.3241x over previous
//
#include <hip/hip_runtime.h>
#include <hip/hip_bf16.h>
#include <stdint.h>

#define NB 512
#define NW 40
#define NE 512
#define NH 512
#define NV 12000
#define G4 2048

typedef unsigned short u16;
typedef unsigned int u32;
typedef unsigned long long u64;
typedef __attribute__((ext_vector_type(8))) short short8;
typedef __attribute__((ext_vector_type(4))) float f32x4;

__device__ __forceinline__ unsigned short f2bf(float f) {
  unsigned int u = __float_as_uint(f);
  u += 0x7FFF + ((u >> 16) & 1);
  return (unsigned short)(u >> 16);
}
__device__ __forceinline__ float bf2f(unsigned short b) {
  return __uint_as_float(((unsigned int)b) << 16);
}
__device__ __forceinline__ float loadIn(const void* p, long i, int bf) {
  return bf ? bf2f(((const u16*)p)[i]) : ((const float*)p)[i];
}

// ---------------- dtype detector ----------------
__global__ void detect_kernel(const u16* p, int* flag) {
  __shared__ int cnt;
  int i = threadIdx.x;
  if (i == 0) cnt = 0;
  __syncthreads();
  unsigned short u = p[2 * (i * 1001)];
  int e = (u >> 7) & 0xFF;
  if (e >= 100 && e <= 126) atomicAdd(&cnt, 1);
  __syncthreads();
  if (i == 0) *flag = (cnt >= 32) ? 1 : 0;
}

// ---------------- tableT = bf16(tanh(lookup_W^T)), (V, E) ----------------
__global__ void table_kernel(const void* lookup, const int* flag, u16* tableT) {
  __shared__ float tile[64][65];
  int bf = *flag;
  int v0 = blockIdx.x * 64, e0 = blockIdx.y * 64;
  int tx = threadIdx.x, ty = threadIdx.y;  // (64,4)
#pragma unroll
  for (int r = 0; r < 16; ++r) {
    int e = r * 4 + ty, v = tx;
    if (v0 + v < NV)
      tile[e][v] = tanhf(loadIn(lookup, (long)(e0 + e) * NV + v0 + v, bf));
  }
  __syncthreads();
#pragma unroll
  for (int r = 0; r < 16; ++r) {
    int v = r * 4 + ty, e = tx;
    if (v0 + v < NV)
      tableT[(long)(v0 + v) * NE + e0 + e] = f2bf(tile[e][v]);
  }
}

// ---------------- emb (W*B, E) bf16, rows tb = t*NB+b ----------------
__global__ void embed_kernel(const int* __restrict__ qv,
                             const u16* __restrict__ tableT,
                             u16* __restrict__ emb) {
  int tid = blockIdx.x * 256 + threadIdx.x;
  int token = tid >> 6;
  int chunk = tid & 63;
  int tt = token / NB, b = token % NB;
  int q = qv[b * NW + tt];
  uint4 val = make_uint4(0u, 0u, 0u, 0u);
  if (q > 0) val = *(const uint4*)(tableT + (long)(q - 1) * NE + chunk * 8);
  *(uint4*)(emb + (long)token * NE + chunk * 8) = val;
}

// ---------------- pack weights: Wc[d] rows = [wih | whh], bf16 ------------
__global__ void pack_kernel(const void* wih0, const void* whh0, const void* b0,
                            const void* wih1, const void* whh1, const void* b1,
                            const int* flag, u16* Wc0, u16* Wc1, float* bsum) {
  const long N0 = 2L * G4 * 1024, N1 = 2L * G4 * 1536;
  long idx = (long)blockIdx.x * 256 + threadIdx.x;
  int bf = *flag;
  if (idx < N0) {
    int d = (int)(idx / (G4 * 1024));
    int rem = (int)(idx % (long)(G4 * 1024));
    int g = rem / 1024, k = rem % 1024;
    float v = (k < 512) ? loadIn(wih0, ((long)d * G4 + g) * 512 + k, bf)
                        : loadIn(whh0, ((long)d * G4 + g) * 512 + (k - 512), bf);
    Wc0[idx] = f2bf(v);
  } else if (idx < N0 + N1) {
    long i2 = idx - N0;
    int d = (int)(i2 / (G4 * 1536));
    int rem = (int)(i2 % (long)(G4 * 1536));
    int g = rem / 1536, k = rem % 1536;
    float v = (k < 1024) ? loadIn(wih1, ((long)d * G4 + g) * 1024 + k, bf)
                         : loadIn(whh1, ((long)d * G4 + g) * 512 + (k - 1024), bf);
    Wc1[i2] = f2bf(v);
  } else if (idx < N0 + N1 + 2L * 2 * G4) {
    long i3 = idx - N0 - N1;  // [layer][d][g]
    int layer = (int)(i3 / (2 * G4));
    int d = (int)((i3 / G4) & 1);
    int g = (int)(i3 % G4);
    const void* bb = layer ? b1 : b0;
    float v = loadIn(bb, (long)d * 2 * G4 + g, bf) +
              loadIn(bb, (long)d * 2 * G4 + G4 + g, bf);
    bsum[i3] = v;
  }
}

// ---------------- zero the barrier (8 KB) ----------------
__global__ void zero_bar(unsigned int* bar) {
  bar[blockIdx.x * 256 + threadIdx.x] = 0u;
}

// ---------------- xg GEMM: xg[t][d][col][b][jn*4+g] = X@Wih^T + bias ------
// 128x128 tile, BK=64, m97-style staging, 4 waves 2x2. (R4-validated.)
__global__ __launch_bounds__(256, 2) void xg_gemm(
    const u16* __restrict__ X, int Kx, int Kfull, const u16* __restrict__ Wc,
    const float* __restrict__ bsumL, u16* __restrict__ xg) {
  __shared__ __align__(16) char lds[32768];  // A 16K + B 16K
  const int tid = threadIdx.x;
  const int lane = tid & 63, wv = tid >> 6;
  const int wm = wv & 1, wn = wv >> 1;
  const int col = lane & 15, quad = lane >> 4;
  const int tb0 = blockIdx.x * 128;
  const int by = blockIdx.y;
  const int d = by >> 4, colb = by & 15, j0 = colb * 32;

  f32x4 zero = {0.f, 0.f, 0.f, 0.f};
  f32x4 acc[4][4];
#pragma unroll
  for (int i = 0; i < 4; ++i)
#pragma unroll
    for (int j = 0; j < 4; ++j) acc[i][j] = zero;

  const int iters = Kx >> 6;
  for (int it = 0; it < iters; ++it) {
    int k0 = it << 6;
#pragma unroll
    for (int p = 0; p < 8; ++p) {
      int c = p * 256 + tid;  // [0,2048)
      const u16* gsrc;
      if (c < 1024) {  // A rows 0..127
        int r = c >> 3, sl = c & 7;
        int kk = k0 + ((sl * 8) ^ ((r & 7) << 3));
        gsrc = X + (long)(tb0 + r) * Kx + kk;
      } else {
        int cb = c - 1024;
        int r = cb >> 3, sl = cb & 7;
        int kk = k0 + ((sl * 8) ^ ((r & 7) << 3));
        int grow = (r >> 5) * 512 + j0 + (r & 31);
        gsrc = Wc + ((long)d * G4 + grow) * Kfull + kk;
      }
      __builtin_amdgcn_global_load_lds(
          (const __attribute__((address_space(1))) void*)(const void*)gsrc,
          (__attribute__((address_space(3))) void*)(lds + p * 4096 + wv * 1024),
          16, 0, 0);
    }
    __syncthreads();
    const u16* As = (const u16*)lds;
    const u16* Bs = (const u16*)(lds + 16384);
#pragma unroll
    for (int ks = 0; ks < 2; ++ks) {
      short8 afr[4], bfr[4];
#pragma unroll
      for (int mf = 0; mf < 4; ++mf) {
        int rm = wm * 64 + mf * 16 + col;
        int sl = (ks * 32 + quad * 8) ^ ((rm & 7) << 3);
        afr[mf] = *(const short8*)(As + rm * 64 + sl);
      }
#pragma unroll
      for (int nf = 0; nf < 4; ++nf) {
        int br = wn * 64 + nf * 16 + col;
        int sl = (ks * 32 + quad * 8) ^ ((br & 7) << 3);
        bfr[nf] = *(const short8*)(Bs + br * 64 + sl);
      }
#pragma unroll
      for (int mf = 0; mf < 4; ++mf)
#pragma unroll
        for (int nf = 0; nf < 4; ++nf)
          acc[mf][nf] = __builtin_amdgcn_mfma_f32_16x16x32_bf16(
              afr[mf], bfr[nf], acc[mf][nf], 0, 0, 0);
    }
    __syncthreads();
  }

  float bias[4];
#pragma unroll
  for (int nf = 0; nf < 4; ++nf) {
    int n = wn * 64 + nf * 16 + col;
    bias[nf] = bsumL[d * G4 + (n >> 5) * 512 + j0 + (n & 31)];
  }
#pragma unroll
  for (int mf = 0; mf < 4; ++mf)
#pragma unroll
    for (int nf = 0; nf < 4; ++nf) {
      int n = wn * 64 + nf * 16 + col;
      int g = n >> 5, jn = n & 31;
#pragma unroll
      for (int r = 0; r < 4; ++r) {
        int m = wm * 64 + mf * 16 + quad * 4 + r;
        int tb = tb0 + m, t = tb >> 9, b = tb & 511;
        long oi = ((((long)t * 2 + d) * 16 + colb) * 512 + b) * 128 + jn * 4 + g;
        xg[oi] = f2bf(acc[mf][nf][r] + bias[nf]);
      }
    }
}

// ---------------- persistent bidirectional LSTM recurrence ----------------
// R7: (1) h_{t-1} staged block-shared via global_load_lds (16B/lane, SC1
// cpol -> LLC-coherent), LDS dbuf: halves LLC traffic (no wn duplication)
// and 4x fewer transactions vs R6's 8B register loads.
// (2) Wave tile = 4 gates x 16 j: every thread holds i,f,g,o for its own
// cells in registers -> gate-exchange LDS round-trip and its 3 syncthreads
// deleted. h packed via 4KB LDS (reusing stage buf) into paired 4B stores.
// (3) xg prefetch issued at step start, hidden under the K-loop.
// Group barrier (16 blocks sharing (mi,d)) unchanged from R6.
__global__ __launch_bounds__(256, 1) void lstm_pers(
    const u16* __restrict__ xg, const u16* __restrict__ Wc, int Kfull, int Kx,
    u16* __restrict__ hbuf, u16* __restrict__ h0cat, void* __restrict__ outp,
    const int* __restrict__ qlen, const int* __restrict__ flag,
    unsigned int* bar, int layer) {
  __shared__ __align__(16) char lds[147456];  // [Whh 128K][h-stage 2x8K]
  const int tid = threadIdx.x;
  const int lane = tid & 63, wv = tid >> 6;
  const int wm = wv & 1, wn = wv >> 1;
  const int col = lane & 15, quad = lane >> 4;
  const int l = blockIdx.x;
  const int colid = l & 31, mi = l >> 5;
  const int colb = colid & 15, j0 = colb * 32, d = colid >> 4;
  const int m0 = mi * 64;
  const int gid = l >> 4;  // == mi*2 + d (16 groups of 16 blocks)

  // ---- preload Whh slice into LDS: rows r=g*32+jn, [128][512] swizzled ----
#pragma unroll
  for (int p = 0; p < 32; ++p) {
    int c = p * 256 + tid;
    int row = c >> 6, rem = c & 63;
    int kc = rem >> 3, sl = rem & 7;
    int grow = (row >> 5) * 512 + j0 + (row & 31);
    int gk = Kx + kc * 64 + ((sl * 8) ^ ((row & 7) << 3));
    const u16* gsrc = Wc + ((long)d * G4 + grow) * Kfull + gk;
    __builtin_amdgcn_global_load_lds(
        (const __attribute__((address_space(1))) void*)(const void*)gsrc,
        (__attribute__((address_space(3))) void*)(lds + p * 4096 + wv * 1024),
        16, 0, 0);
  }
  const u16* Bs = (const u16*)lds;
  char* hstg = lds + 131072;     // 2 x 8 KB stage bufs; also 4 KB h-pack
  u16* hLDS = (u16*)hstg;        // epilogue pack [64 m][32 jn]

  float creg[2][4];
#pragma unroll
  for (int i = 0; i < 2; ++i)
#pragma unroll
    for (int r = 0; r < 4; ++r) creg[i][r] = 0.f;
  const int isbf = *flag;
  f32x4 zero = {0.f, 0.f, 0.f, 0.f};

  __syncthreads();  // Whh resident

#pragma unroll 1
  for (int t = 0; t < NW; ++t) {
    const int tq = d ? (NW - 1 - t) : t;

    // xg prefetch: thread cell (m = wm*32+mf*16+quad*4+r, j = wn*16+col)
    ushort4 xgv[2][4];
    const u16* xgt = xg + ((((long)tq * 2 + d) * 16 + colb) * 512 + m0) * 128;
#pragma unroll
    for (int mf = 0; mf < 2; ++mf)
#pragma unroll
      for (int r = 0; r < 4; ++r) {
        int m = wm * 32 + mf * 16 + quad * 4 + r;
        xgv[mf][r] = *(const ushort4*)(xgt + m * 128 + (wn * 16 + col) * 4);
      }

    f32x4 acc[2][4];  // [mf][gate]
#pragma unroll
    for (int i = 0; i < 2; ++i)
#pragma unroll
      for (int j = 0; j < 4; ++j) acc[i][j] = zero;

    if (t > 0) {
      const u16* hp =
          hbuf + ((t - 1) & 1) * (2L * NB * NH) + ((long)d * NB + m0) * NH;
      // stage h chunk (64 rows x 64 k = 8 KB) via LDS-DMA, SC1 (LLC read)
      auto stage = [&](int it, int pb) {
        char* dst = hstg + pb * 8192;
#pragma unroll
        for (int p = 0; p < 2; ++p) {
          int c = p * 256 + tid;  // [0,512)
          int row = c >> 3, ck = c & 7;
          int kk = it * 64 + ((ck * 8) ^ ((row & 7) << 3));
          const u16* gsrc = hp + (long)row * NH + kk;
          __builtin_amdgcn_global_load_lds(
              (const __attribute__((address_space(1))) void*)(const void*)gsrc,
              (__attribute__((address_space(3))) void*)(dst + p * 4096 +
                                                        wv * 1024),
              16, 0, 16 /* SC1: agent-coherent read from LLC */);
        }
      };
      stage(0, 0);
      __syncthreads();
#pragma unroll 1
      for (int it = 0; it < 8; ++it) {
        if (it + 1 < 8) stage(it + 1, (it + 1) & 1);
        const u16* As = (const u16*)(hstg + (it & 1) * 8192);
#pragma unroll
        for (int ks = 0; ks < 2; ++ks) {
          short8 afr[2], bfr[4];
#pragma unroll
          for (int mf = 0; mf < 2; ++mf) {
            int rm = wm * 32 + mf * 16 + col;
            int sl = (ks * 32 + quad * 8) ^ ((rm & 7) << 3);
            afr[mf] = *(const short8*)(As + rm * 64 + sl);
          }
#pragma unroll
          for (int g = 0; g < 4; ++g) {
            int br = g * 32 + wn * 16 + col;
            int sl = (ks * 32 + quad * 8) ^ ((br & 7) << 3);
            bfr[g] = *(const short8*)(Bs + br * 512 + it * 64 + sl);
          }
#pragma unroll
          for (int mf = 0; mf < 2; ++mf)
#pragma unroll
            for (int g = 0; g < 4; ++g)
              acc[mf][g] = __builtin_amdgcn_mfma_f32_16x16x32_bf16(
                  afr[mf], bfr[g], acc[mf][g], 0, 0, 0);
        }
        __syncthreads();
      }
    }

    // ---- register-only cell update; pack h into 4 KB LDS ----
#pragma unroll
    for (int mf = 0; mf < 2; ++mf)
#pragma unroll
      for (int r = 0; r < 4; ++r) {
        int m = wm * 32 + mf * 16 + quad * 4 + r;
        const u16* xv = (const u16*)&xgv[mf][r];
        float gi = acc[mf][0][r] + bf2f(xv[0]);
        float gf = acc[mf][1][r] + bf2f(xv[1]);
        float gg = acc[mf][2][r] + bf2f(xv[2]);
        float go = acc[mf][3][r] + bf2f(xv[3]);
        float si = 1.f / (1.f + __expf(-gi));
        float sf = 1.f / (1.f + __expf(-gf));
        float so = 1.f / (1.f + __expf(-go));
        float cn = sf * creg[mf][r] + si * tanhf(gg);
        float h = so * tanhf(cn);
        creg[mf][r] = cn;
        hLDS[m * 32 + wn * 16 + col] = f2bf(h);
        // fp32 output path: store full-precision h directly (rare rows)
        if (layer == 1 && !isbf) {
          int bg = m0 + m;
          if (qlen[bg] - 1 == tq)
            ((float*)outp)[(long)bg * (2 * NH) + d * NH + j0 + wn * 16 + col] =
                h;
        }
      }
    __syncthreads();

    // ---- paired coalesced stores from the pack ----
    u16* hnxt = hbuf + (t & 1) * (2L * NB * NH);
#pragma unroll
    for (int p = 0; p < 4; ++p) {
      int c = p * 256 + tid;  // [0,1024) pairs
      int m = c >> 4, pr = c & 15;
      u32 hw = ((const u32*)hLDS)[m * 16 + pr];
      int bg = m0 + m, jg = j0 + pr * 2;
      __hip_atomic_store((u32*)(hnxt + ((long)d * NB + bg) * NH + jg), hw,
                         __ATOMIC_RELAXED, __HIP_MEMORY_SCOPE_AGENT);
      if (layer == 0) {
        *(u32*)(h0cat + ((long)tq * NB + bg) * (2 * NH) + d * NH + jg) = hw;
      } else if (isbf && qlen[bg] - 1 == tq) {
        *(u32*)((u16*)outp + (long)bg * (2 * NH) + d * NH + jg) = hw;
      }
    }

    // ---- group barrier (16 blocks sharing (mi,d)), relaxed agent atomics --
    if (t < NW - 1) {
      __syncthreads();  // drains vmcnt: h sc1 stores visible at LLC
      if (tid == 0) {
        u32* cnt = &bar[gid * 64];
        u32* flg = &bar[1024 + gid * 64];
        unsigned old = __hip_atomic_fetch_add(cnt, 1u, __ATOMIC_RELAXED,
                                              __HIP_MEMORY_SCOPE_AGENT);
        if (old == 16u * (t + 1) - 1u)
          __hip_atomic_store(flg, (unsigned)(t + 1), __ATOMIC_RELAXED,
                             __HIP_MEMORY_SCOPE_AGENT);
        else
          while (__hip_atomic_load(flg, __ATOMIC_RELAXED,
                                   __HIP_MEMORY_SCOPE_AGENT) <
                 (unsigned)(t + 1))
            __builtin_amdgcn_s_sleep(1);
      }
      __syncthreads();
    }
  }
}

extern "C" void kernel_launch(void* const* d_in, const int* in_sizes, int n_in,
                              void* d_out, int out_size, void* d_ws,
                              size_t ws_size, hipStream_t stream) {
  const int* qv = (const int*)d_in[0];
  const int* ql = (const int*)d_in[1];
  const void* lookup = d_in[2];
  const void* wih0 = d_in[3];
  const void* whh0 = d_in[4];
  const void* b0 = d_in[5];
  const void* wih1 = d_in[6];
  const void* whh1 = d_in[7];
  const void* b1 = d_in[8];

  char* ws = (char*)d_ws;
  size_t off = 0;
  int* flag = (int*)ws;                 off += 256;
  unsigned int* bar = (unsigned int*)(ws + off); off += 8192;
  float* bsum = (float*)(ws + off);     off += 2L * 2 * G4 * 4;        // 32 KB
  u16* Wc0 = (u16*)(ws + off);          off += 2L * G4 * 1024 * 2;     // 8 MB
  u16* Wc1 = (u16*)(ws + off);          off += 2L * G4 * 1536 * 2;     // 12 MB
  u16* hbuf = (u16*)(ws + off);         off += 2L * 2 * NB * NH * 2;   // 2 MB
  u16* h0cat = (u16*)(ws + off);        off += (size_t)NW * NB * 2 * NH * 2; // 40 MB
  u16* emb = (u16*)(ws + off);          off += (size_t)NW * NB * NE * 2;     // 20 MB
  u16* xg = (u16*)(ws + off);           off += (size_t)NW * 2 * 16 * 512 * 128 * 2; // 168 MB
  u16* tableT = h0cat;  // tableT (12.3 MB) aliases h0cat: dead before layer0

  detect_kernel<<<1, 64, 0, stream>>>((const u16*)lookup, flag);
  table_kernel<<<dim3(188, 8), dim3(64, 4), 0, stream>>>(lookup, flag, tableT);
  {
    long total = 2L * G4 * 1024 + 2L * G4 * 1536 + 2L * 2 * G4;
    int blocks = (int)((total + 255) / 256);
    pack_kernel<<<blocks, 256, 0, stream>>>(wih0, whh0, b0, wih1, whh1, b1,
                                            flag, Wc0, Wc1, bsum);
  }
  embed_kernel<<<NW * NB / 4, 256, 0, stream>>>(qv, tableT, emb);

  // layer 0
  xg_gemm<<<dim3(160, 32), 256, 0, stream>>>(emb, 512, 1024, Wc0, bsum, xg);
  zero_bar<<<8, 256, 0, stream>>>(bar);
  lstm_pers<<<256, 256, 0, stream>>>(xg, Wc0, 1024, 512, hbuf, h0cat, d_out,
                                     ql, flag, bar, 0);
  // layer 1
  xg_gemm<<<dim3(160, 32), 256, 0, stream>>>(h0cat, 1024, 1536, Wc1,
                                             bsum + 2 * G4, xg);
  zero_bar<<<8, 256, 0, stream>>>(bar);
  lstm_pers<<<256, 256, 0, stream>>>(xg, Wc1, 1536, 1024, hbuf, h0cat, d_out,
                                     ql, flag, bar, 1);
}

// Round 8
// 971.319 us; speedup vs baseline: 4.0380x; 1.0468x over previous
//
#include <hip/hip_runtime.h>
#include <hip/hip_bf16.h>
#include <stdint.h>

#define NB 512
#define NW 40
#define NE 512
#define NH 512
#define NV 12000
#define G4 2048

typedef unsigned short u16;
typedef unsigned int u32;
typedef unsigned long long u64;
typedef __attribute__((ext_vector_type(8))) short short8;
typedef __attribute__((ext_vector_type(4))) float f32x4;

__device__ __forceinline__ unsigned short f2bf(float f) {
  unsigned int u = __float_as_uint(f);
  u += 0x7FFF + ((u >> 16) & 1);
  return (unsigned short)(u >> 16);
}
__device__ __forceinline__ float bf2f(unsigned short b) {
  return __uint_as_float(((unsigned int)b) << 16);
}
__device__ __forceinline__ float loadIn(const void* p, long i, int bf) {
  return bf ? bf2f(((const u16*)p)[i]) : ((const float*)p)[i];
}

// ---------------- dtype detector ----------------
__global__ void detect_kernel(const u16* p, int* flag) {
  __shared__ int cnt;
  int i = threadIdx.x;
  if (i == 0) cnt = 0;
  __syncthreads();
  unsigned short u = p[2 * (i * 1001)];
  int e = (u >> 7) & 0xFF;
  if (e >= 100 && e <= 126) atomicAdd(&cnt, 1);
  __syncthreads();
  if (i == 0) *flag = (cnt >= 32) ? 1 : 0;
}

// ---------------- tableT = bf16(tanh(lookup_W^T)), (V, E) ----------------
__global__ void table_kernel(const void* lookup, const int* flag, u16* tableT) {
  __shared__ float tile[64][65];
  int bf = *flag;
  int v0 = blockIdx.x * 64, e0 = blockIdx.y * 64;
  int tx = threadIdx.x, ty = threadIdx.y;  // (64,4)
#pragma unroll
  for (int r = 0; r < 16; ++r) {
    int e = r * 4 + ty, v = tx;
    if (v0 + v < NV)
      tile[e][v] = tanhf(loadIn(lookup, (long)(e0 + e) * NV + v0 + v, bf));
  }
  __syncthreads();
#pragma unroll
  for (int r = 0; r < 16; ++r) {
    int v = r * 4 + ty, e = tx;
    if (v0 + v < NV)
      tableT[(long)(v0 + v) * NE + e0 + e] = f2bf(tile[e][v]);
  }
}

// ---------------- emb (W*B, E) bf16, rows tb = t*NB+b ----------------
__global__ void embed_kernel(const int* __restrict__ qv,
                             const u16* __restrict__ tableT,
                             u16* __restrict__ emb) {
  int tid = blockIdx.x * 256 + threadIdx.x;
  int token = tid >> 6;
  int chunk = tid & 63;
  int tt = token / NB, b = token % NB;
  int q = qv[b * NW + tt];
  uint4 val = make_uint4(0u, 0u, 0u, 0u);
  if (q > 0) val = *(const uint4*)(tableT + (long)(q - 1) * NE + chunk * 8);
  *(uint4*)(emb + (long)token * NE + chunk * 8) = val;
}

// ---------------- pack weights: Wc[d] rows = [wih | whh], bf16 ------------
__global__ void pack_kernel(const void* wih0, const void* whh0, const void* b0,
                            const void* wih1, const void* whh1, const void* b1,
                            const int* flag, u16* Wc0, u16* Wc1, float* bsum) {
  const long N0 = 2L * G4 * 1024, N1 = 2L * G4 * 1536;
  long idx = (long)blockIdx.x * 256 + threadIdx.x;
  int bf = *flag;
  if (idx < N0) {
    int d = (int)(idx / (G4 * 1024));
    int rem = (int)(idx % (long)(G4 * 1024));
    int g = rem / 1024, k = rem % 1024;
    float v = (k < 512) ? loadIn(wih0, ((long)d * G4 + g) * 512 + k, bf)
                        : loadIn(whh0, ((long)d * G4 + g) * 512 + (k - 512), bf);
    Wc0[idx] = f2bf(v);
  } else if (idx < N0 + N1) {
    long i2 = idx - N0;
    int d = (int)(i2 / (G4 * 1536));
    int rem = (int)(i2 % (long)(G4 * 1536));
    int g = rem / 1536, k = rem % 1536;
    float v = (k < 1024) ? loadIn(wih1, ((long)d * G4 + g) * 1024 + k, bf)
                         : loadIn(whh1, ((long)d * G4 + g) * 512 + (k - 1024), bf);
    Wc1[i2] = f2bf(v);
  } else if (idx < N0 + N1 + 2L * 2 * G4) {
    long i3 = idx - N0 - N1;  // [layer][d][g]
    int layer = (int)(i3 / (2 * G4));
    int d = (int)((i3 / G4) & 1);
    int g = (int)(i3 % G4);
    const void* bb = layer ? b1 : b0;
    float v = loadIn(bb, (long)d * 2 * G4 + g, bf) +
              loadIn(bb, (long)d * 2 * G4 + G4 + g, bf);
    bsum[i3] = v;
  }
}

// ---------------- zero the barrier (8 KB) ----------------
__global__ void zero_bar(unsigned int* bar) {
  bar[blockIdx.x * 256 + threadIdx.x] = 0u;
}

// ---------------- xg GEMM: xg[t][d][col][b][jn*4+g] = X@Wih^T + bias ------
// 128x128 tile, BK=64, m97-style staging, 4 waves 2x2.
// R8: 1D grid + supertile swizzle (4 bx x 8 by contiguous) so A-tiles
// (4x256KB) and B-tiles (8x256KB) stay cache-resident across reuse --
// R7 showed 346 MB HBM FETCH (7x the ideal) from bx-fastest streaming.
__global__ __launch_bounds__(256, 2) void xg_gemm(
    const u16* __restrict__ X, int Kx, int Kfull, const u16* __restrict__ Wc,
    const float* __restrict__ bsumL, u16* __restrict__ xg) {
  __shared__ __align__(16) char lds[32768];  // A 16K + B 16K
  const int tid = threadIdx.x;
  const int lane = tid & 63, wv = tid >> 6;
  const int wm = wv & 1, wn = wv >> 1;
  const int col = lane & 15, quad = lane >> 4;
  const int s = blockIdx.x >> 5, w = blockIdx.x & 31;
  const int bx = (s % 40) * 4 + (w & 3);
  const int by = (s / 40) * 8 + (w >> 2);
  const int tb0 = bx * 128;
  const int d = by >> 4, colb = by & 15, j0 = colb * 32;

  f32x4 zero = {0.f, 0.f, 0.f, 0.f};
  f32x4 acc[4][4];
#pragma unroll
  for (int i = 0; i < 4; ++i)
#pragma unroll
    for (int j = 0; j < 4; ++j) acc[i][j] = zero;

  const int iters = Kx >> 6;
  for (int it = 0; it < iters; ++it) {
    int k0 = it << 6;
#pragma unroll
    for (int p = 0; p < 8; ++p) {
      int c = p * 256 + tid;  // [0,2048)
      const u16* gsrc;
      if (c < 1024) {  // A rows 0..127
        int r = c >> 3, sl = c & 7;
        int kk = k0 + ((sl * 8) ^ ((r & 7) << 3));
        gsrc = X + (long)(tb0 + r) * Kx + kk;
      } else {
        int cb = c - 1024;
        int r = cb >> 3, sl = cb & 7;
        int kk = k0 + ((sl * 8) ^ ((r & 7) << 3));
        int grow = (r >> 5) * 512 + j0 + (r & 31);
        gsrc = Wc + ((long)d * G4 + grow) * Kfull + kk;
      }
      __builtin_amdgcn_global_load_lds(
          (const __attribute__((address_space(1))) void*)(const void*)gsrc,
          (__attribute__((address_space(3))) void*)(lds + p * 4096 + wv * 1024),
          16, 0, 0);
    }
    __syncthreads();
    const u16* As = (const u16*)lds;
    const u16* Bs = (const u16*)(lds + 16384);
#pragma unroll
    for (int ks = 0; ks < 2; ++ks) {
      short8 afr[4], bfr[4];
#pragma unroll
      for (int mf = 0; mf < 4; ++mf) {
        int rm = wm * 64 + mf * 16 + col;
        int sl = (ks * 32 + quad * 8) ^ ((rm & 7) << 3);
        afr[mf] = *(const short8*)(As + rm * 64 + sl);
      }
#pragma unroll
      for (int nf = 0; nf < 4; ++nf) {
        int br = wn * 64 + nf * 16 + col;
        int sl = (ks * 32 + quad * 8) ^ ((br & 7) << 3);
        bfr[nf] = *(const short8*)(Bs + br * 64 + sl);
      }
#pragma unroll
      for (int mf = 0; mf < 4; ++mf)
#pragma unroll
        for (int nf = 0; nf < 4; ++nf)
          acc[mf][nf] = __builtin_amdgcn_mfma_f32_16x16x32_bf16(
              afr[mf], bfr[nf], acc[mf][nf], 0, 0, 0);
    }
    __syncthreads();
  }

  float bias[4];
#pragma unroll
  for (int nf = 0; nf < 4; ++nf) {
    int n = wn * 64 + nf * 16 + col;
    bias[nf] = bsumL[d * G4 + (n >> 5) * 512 + j0 + (n & 31)];
  }
#pragma unroll
  for (int mf = 0; mf < 4; ++mf)
#pragma unroll
    for (int nf = 0; nf < 4; ++nf) {
      int n = wn * 64 + nf * 16 + col;
      int g = n >> 5, jn = n & 31;
#pragma unroll
      for (int r = 0; r < 4; ++r) {
        int m = wm * 64 + mf * 16 + quad * 4 + r;
        int tb = tb0 + m, t = tb >> 9, b = tb & 511;
        long oi = ((((long)t * 2 + d) * 16 + colb) * 512 + b) * 128 + jn * 4 + g;
        xg[oi] = f2bf(acc[mf][nf][r] + bias[nf]);
      }
    }
}

// ---------------- persistent bidirectional LSTM recurrence ----------------
// R8: BK 64->128 (4 K-iters instead of 8): each K-iter barrier drains the
// next chunk's full LLC latency (only 4 waves/CU to hide it), so halving
// the iter count halves the dominant per-step stall. LDS = Whh 128K +
// 2x16K dbuf = exactly 160 KiB. Last K-iter barrier dropped (epilogue's
// own syncthreads covers the hazard). Rest identical to R7.
__global__ __launch_bounds__(256, 1) void lstm_pers(
    const u16* __restrict__ xg, const u16* __restrict__ Wc, int Kfull, int Kx,
    u16* __restrict__ hbuf, u16* __restrict__ h0cat, void* __restrict__ outp,
    const int* __restrict__ qlen, const int* __restrict__ flag,
    unsigned int* bar, int layer) {
  __shared__ __align__(16) char lds[163840];  // [Whh 128K][h-stage 2x16K]
  const int tid = threadIdx.x;
  const int lane = tid & 63, wv = tid >> 6;
  const int wm = wv & 1, wn = wv >> 1;
  const int col = lane & 15, quad = lane >> 4;
  const int l = blockIdx.x;
  const int colid = l & 31, mi = l >> 5;
  const int colb = colid & 15, j0 = colb * 32, d = colid >> 4;
  const int m0 = mi * 64;
  const int gid = l >> 4;  // == mi*2 + d (16 groups of 16 blocks)

  // ---- preload Whh slice into LDS: rows r=g*32+jn, [128][512] swizzled ----
#pragma unroll
  for (int p = 0; p < 32; ++p) {
    int c = p * 256 + tid;
    int row = c >> 6, rem = c & 63;
    int kc = rem >> 3, sl = rem & 7;
    int grow = (row >> 5) * 512 + j0 + (row & 31);
    int gk = Kx + kc * 64 + ((sl * 8) ^ ((row & 7) << 3));
    const u16* gsrc = Wc + ((long)d * G4 + grow) * Kfull + gk;
    __builtin_amdgcn_global_load_lds(
        (const __attribute__((address_space(1))) void*)(const void*)gsrc,
        (__attribute__((address_space(3))) void*)(lds + p * 4096 + wv * 1024),
        16, 0, 0);
  }
  const u16* Bs = (const u16*)lds;
  char* hstg = lds + 131072;  // 2 x 16 KB stage bufs; first 4 KB = h-pack
  u16* hLDS = (u16*)hstg;     // epilogue pack [64 m][32 jn]

  float creg[2][4];
#pragma unroll
  for (int i = 0; i < 2; ++i)
#pragma unroll
    for (int r = 0; r < 4; ++r) creg[i][r] = 0.f;
  const int isbf = *flag;
  f32x4 zero = {0.f, 0.f, 0.f, 0.f};

  __syncthreads();  // Whh resident

#pragma unroll 1
  for (int t = 0; t < NW; ++t) {
    const int tq = d ? (NW - 1 - t) : t;

    // xg prefetch: thread cell (m = wm*32+mf*16+quad*4+r, j = wn*16+col)
    ushort4 xgv[2][4];
    const u16* xgt = xg + ((((long)tq * 2 + d) * 16 + colb) * 512 + m0) * 128;
#pragma unroll
    for (int mf = 0; mf < 2; ++mf)
#pragma unroll
      for (int r = 0; r < 4; ++r) {
        int m = wm * 32 + mf * 16 + quad * 4 + r;
        xgv[mf][r] = *(const ushort4*)(xgt + m * 128 + (wn * 16 + col) * 4);
      }

    f32x4 acc[2][4];  // [mf][gate]
#pragma unroll
    for (int i = 0; i < 2; ++i)
#pragma unroll
      for (int j = 0; j < 4; ++j) acc[i][j] = zero;

    if (t > 0) {
      const u16* hp =
          hbuf + ((t - 1) & 1) * (2L * NB * NH) + ((long)d * NB + m0) * NH;
      // stage h chunk (64 rows x 128 k = 16 KB) via LDS-DMA, SC1 (LLC read)
      auto stage = [&](int it, int pb) {
        char* dst = hstg + pb * 16384;
#pragma unroll
        for (int p = 0; p < 4; ++p) {
          int c = p * 256 + tid;  // [0,1024)
          int row = c >> 4, slot = c & 15;
          int half = slot >> 3, ck = slot & 7;
          int kk = it * 128 + half * 64 + ((ck * 8) ^ ((row & 7) << 3));
          const u16* gsrc = hp + (long)row * NH + kk;
          __builtin_amdgcn_global_load_lds(
              (const __attribute__((address_space(1))) void*)(const void*)gsrc,
              (__attribute__((address_space(3))) void*)(dst + p * 4096 +
                                                        wv * 1024),
              16, 0, 16 /* SC1: agent-coherent read from LLC */);
        }
      };
      stage(0, 0);
      __syncthreads();
#pragma unroll 1
      for (int it = 0; it < 4; ++it) {
        if (it + 1 < 4) stage(it + 1, (it + 1) & 1);
        const u16* As = (const u16*)(hstg + (it & 1) * 16384);
#pragma unroll
        for (int ks = 0; ks < 4; ++ks) {
          short8 afr[2], bfr[4];
          const int ksub = ks * 32 + quad * 8;  // [0,128)
#pragma unroll
          for (int mf = 0; mf < 2; ++mf) {
            int rm = wm * 32 + mf * 16 + col;
            int sl = (ksub & 63) ^ ((rm & 7) << 3);
            afr[mf] = *(const short8*)(As + rm * 128 + (ksub & 64) + sl);
          }
          const int kc = it * 128 + ksub;
#pragma unroll
          for (int g = 0; g < 4; ++g) {
            int br = g * 32 + wn * 16 + col;
            int sl = (kc & 63) ^ ((br & 7) << 3);
            bfr[g] = *(const short8*)(Bs + br * 512 + (kc & ~63) + sl);
          }
#pragma unroll
          for (int mf = 0; mf < 2; ++mf)
#pragma unroll
            for (int g = 0; g < 4; ++g)
              acc[mf][g] = __builtin_amdgcn_mfma_f32_16x16x32_bf16(
                  afr[mf], bfr[g], acc[mf][g], 0, 0, 0);
        }
        if (it + 1 < 4) __syncthreads();
      }
    }

    // ---- register-only cell update; pack h into 4 KB LDS ----
#pragma unroll
    for (int mf = 0; mf < 2; ++mf)
#pragma unroll
      for (int r = 0; r < 4; ++r) {
        int m = wm * 32 + mf * 16 + quad * 4 + r;
        const u16* xv = (const u16*)&xgv[mf][r];
        float gi = acc[mf][0][r] + bf2f(xv[0]);
        float gf = acc[mf][1][r] + bf2f(xv[1]);
        float gg = acc[mf][2][r] + bf2f(xv[2]);
        float go = acc[mf][3][r] + bf2f(xv[3]);
        float si = 1.f / (1.f + __expf(-gi));
        float sf = 1.f / (1.f + __expf(-gf));
        float so = 1.f / (1.f + __expf(-go));
        float cn = sf * creg[mf][r] + si * tanhf(gg);
        float h = so * tanhf(cn);
        creg[mf][r] = cn;
        hLDS[m * 32 + wn * 16 + col] = f2bf(h);
        // fp32 output path: store full-precision h directly (rare rows)
        if (layer == 1 && !isbf) {
          int bg = m0 + m;
          if (qlen[bg] - 1 == tq)
            ((float*)outp)[(long)bg * (2 * NH) + d * NH + j0 + wn * 16 + col] =
                h;
        }
      }
    __syncthreads();

    // ---- paired coalesced stores from the pack ----
    u16* hnxt = hbuf + (t & 1) * (2L * NB * NH);
#pragma unroll
    for (int p = 0; p < 4; ++p) {
      int c = p * 256 + tid;  // [0,1024) pairs
      int m = c >> 4, pr = c & 15;
      u32 hw = ((const u32*)hLDS)[m * 16 + pr];
      int bg = m0 + m, jg = j0 + pr * 2;
      __hip_atomic_store((u32*)(hnxt + ((long)d * NB + bg) * NH + jg), hw,
                         __ATOMIC_RELAXED, __HIP_MEMORY_SCOPE_AGENT);
      if (layer == 0) {
        *(u32*)(h0cat + ((long)tq * NB + bg) * (2 * NH) + d * NH + jg) = hw;
      } else if (isbf && qlen[bg] - 1 == tq) {
        *(u32*)((u16*)outp + (long)bg * (2 * NH) + d * NH + jg) = hw;
      }
    }

    // ---- group barrier (16 blocks sharing (mi,d)), relaxed agent atomics --
    if (t < NW - 1) {
      __syncthreads();  // drains vmcnt: h sc1 stores visible at LLC
      if (tid == 0) {
        u32* cnt = &bar[gid * 64];
        u32* flg = &bar[1024 + gid * 64];
        unsigned old = __hip_atomic_fetch_add(cnt, 1u, __ATOMIC_RELAXED,
                                              __HIP_MEMORY_SCOPE_AGENT);
        if (old == 16u * (t + 1) - 1u)
          __hip_atomic_store(flg, (unsigned)(t + 1), __ATOMIC_RELAXED,
                             __HIP_MEMORY_SCOPE_AGENT);
        else
          while (__hip_atomic_load(flg, __ATOMIC_RELAXED,
                                   __HIP_MEMORY_SCOPE_AGENT) <
                 (unsigned)(t + 1))
            __builtin_amdgcn_s_sleep(1);
      }
      __syncthreads();
    }
  }
}

extern "C" void kernel_launch(void* const* d_in, const int* in_sizes, int n_in,
                              void* d_out, int out_size, void* d_ws,
                              size_t ws_size, hipStream_t stream) {
  const int* qv = (const int*)d_in[0];
  const int* ql = (const int*)d_in[1];
  const void* lookup = d_in[2];
  const void* wih0 = d_in[3];
  const void* whh0 = d_in[4];
  const void* b0 = d_in[5];
  const void* wih1 = d_in[6];
  const void* whh1 = d_in[7];
  const void* b1 = d_in[8];

  char* ws = (char*)d_ws;
  size_t off = 0;
  int* flag = (int*)ws;                 off += 256;
  unsigned int* bar = (unsigned int*)(ws + off); off += 8192;
  float* bsum = (float*)(ws + off);     off += 2L * 2 * G4 * 4;        // 32 KB
  u16* Wc0 = (u16*)(ws + off);          off += 2L * G4 * 1024 * 2;     // 8 MB
  u16* Wc1 = (u16*)(ws + off);          off += 2L * G4 * 1536 * 2;     // 12 MB
  u16* hbuf = (u16*)(ws + off);         off += 2L * 2 * NB * NH * 2;   // 2 MB
  u16* h0cat = (u16*)(ws + off);        off += (size_t)NW * NB * 2 * NH * 2; // 40 MB
  u16* emb = (u16*)(ws + off);          off += (size_t)NW * NB * NE * 2;     // 20 MB
  u16* xg = (u16*)(ws + off);           off += (size_t)NW * 2 * 16 * 512 * 128 * 2; // 168 MB
  u16* tableT = h0cat;  // tableT (12.3 MB) aliases h0cat: dead before layer0

  detect_kernel<<<1, 64, 0, stream>>>((const u16*)lookup, flag);
  table_kernel<<<dim3(188, 8), dim3(64, 4), 0, stream>>>(lookup, flag, tableT);
  {
    long total = 2L * G4 * 1024 + 2L * G4 * 1536 + 2L * 2 * G4;
    int blocks = (int)((total + 255) / 256);
    pack_kernel<<<blocks, 256, 0, stream>>>(wih0, whh0, b0, wih1, whh1, b1,
                                            flag, Wc0, Wc1, bsum);
  }
  embed_kernel<<<NW * NB / 4, 256, 0, stream>>>(qv, tableT, emb);

  // layer 0
  xg_gemm<<<5120, 256, 0, stream>>>(emb, 512, 1024, Wc0, bsum, xg);
  zero_bar<<<8, 256, 0, stream>>>(bar);
  lstm_pers<<<256, 256, 0, stream>>>(xg, Wc0, 1024, 512, hbuf, h0cat, d_out,
                                     ql, flag, bar, 0);
  // layer 1
  xg_gemm<<<5120, 256, 0, stream>>>(h0cat, 1024, 1536, Wc1, bsum + 2 * G4, xg);
  zero_bar<<<8, 256, 0, stream>>>(bar);
  lstm_pers<<<256, 256, 0, stream>>>(xg, Wc1, 1536, 1024, hbuf, h0cat, d_out,
                                     ql, flag, bar, 1);
}